// Round 1
// baseline (260.195 us; speedup 1.0000x reference)
//
#include <hip/hip_runtime.h>
#include <hip/hip_fp16.h>
#include <math.h>

// Problem constants
#define BB   8
#define HW   4096
#define BHW  32768
#define DIM  256
#define CR   64
#define GC   32
#define NHD  4
#define HC   16
#define NTAP 9
#define NCLS 80

// workspace layout (float offsets)
#define OFF_QP   0u          // q planar   [B][64][H][W] fp32       2,097,152
#define OFF_QT   2097152u    // q pix-major[B*HW][64] fp16          1,048,576 (floats of space)
#define OFF_KT   4194304u    // KV fp16 [BG][HW][2 sub][k16|v16]    2,097,152 (floats of space)
#define OFF_T    8388608u    // (unused by fused path; WBF/AB live here)
#define OFF_WBF  8388608u    // W_qkv·g1 bf16 [192][256]            24,576 float-slots
#define OFF_AB   8437760u    // A[192], B[192]                      384
#define OFF_OFFB 10485760u   // off planar [BG][18][H][W]           1,179,648
#define OFF_AOT  11665408u   // attn out bf16 [B*HW][64] pix-major  1,048,576 float-slots used
#define OFF_WPT  13762560u   // wproj bf16 [256][64]                8,192 float-slots used
#define OFF_WCT  13778944u   // wcls  bf16 [80][256]                10,240 float-slots used
#define OFF_WFT  13799424u   // woff^T  [9][32][18]                 5,184

typedef short bf16x8 __attribute__((ext_vector_type(8)));
typedef float f32x4  __attribute__((ext_vector_type(4)));

__device__ __forceinline__ unsigned short f2bf(float f) {
    unsigned u = __float_as_uint(f);
    unsigned r = u + 0x7FFFu + ((u >> 16) & 1u);   // round-to-nearest-even
    return (unsigned short)(r >> 16);
}

// ---------------- k0: weight prep ----------------
__global__ __launch_bounds__(256) void k0_prep(
    const float* __restrict__ wqkv, const float* __restrict__ g1,
    const float* __restrict__ b1, const float* __restrict__ woff,
    const float* __restrict__ wproj, const float* __restrict__ wcls,
    float* __restrict__ ws)
{
    const int t = threadIdx.x;
    const int blk = blockIdx.x;
    if (blk < 192) {
        const int o = blk;
        unsigned short* wbf = (unsigned short*)(ws + OFF_WBF);
        wbf[o * 256 + t] = f2bf(wqkv[o * 256 + t] * g1[t]);
    } else if (blk < 448) {
        const int r = blk - 192;   // 0..255
        unsigned short* wpb = (unsigned short*)(ws + OFF_WPT);
        unsigned short* wcb = (unsigned short*)(ws + OFF_WCT);
        if (t < 64) wpb[r * 64 + t] = f2bf(wproj[r * 64 + t]);
        if (r < 80) wcb[r * 256 + t] = f2bf(wcls[r * 256 + t]);
    } else {
        if (t < 192) {
            float a = 0.f, bb = 0.f;
            for (int c = 0; c < 256; ++c) {
                float w = wqkv[t * 256 + c];
                a += w * g1[c]; bb += w * b1[c];
            }
            ws[OFF_AB + t] = a;
            ws[OFF_AB + 192 + t] = bb;
            for (int pair = t; pair < 288; pair += 192) {
                int wo = pair >> 5, ic = pair & 31;
                for (int o = 0; o < 18; ++o)
                    ws[OFF_WFT + (wo * 32 + ic) * 18 + o] = woff[(o * 32 + ic) * 9 + wo];
            }
        }
    }
}

// ------ k1: QKV GEMM via bf16 MFMA, LN folded in epilogue, fp16 q/KV out ------
__global__ __launch_bounds__(512) void k1_mfma(
    const float* __restrict__ x, float* __restrict__ ws)
{
    __shared__ float tile[64 * 193];   // 49.4 KB transpose tile [px][o] pad 193
    const int t = threadIdx.x;
    const int b = blockIdx.x & 7, row = blockIdx.x >> 3;
    const int wv = __builtin_amdgcn_readfirstlane(t >> 6);
    const int pt = wv & 3, oh = wv >> 2;
    const int lane = t & 63;
    const int quad = lane >> 4, pxl = lane & 15;
    const int colbase = row * 64 + pt * 16 + pxl;
    const unsigned short* wbf = (const unsigned short*)(ws + OFF_WBF);
    const float* AB = ws + OFF_AB;

    f32x4 acc[6];
    #pragma unroll
    for (int ot = 0; ot < 6; ++ot) acc[ot] = (f32x4){0.f, 0.f, 0.f, 0.f};
    float s = 0.f, ss = 0.f;
    const size_t xb0 = (size_t)b * DIM * HW + colbase;

    for (int ks = 0; ks < 8; ++ks) {
        const int cbase = ks * 32 + quad * 8;
        float xv[8];
        #pragma unroll
        for (int j = 0; j < 8; ++j) {
            xv[j] = x[xb0 + (size_t)(cbase + j) * HW];
            s += xv[j]; ss += xv[j] * xv[j];
        }
        union { bf16x8 v; unsigned short u[8]; } bfrag;
        #pragma unroll
        for (int j = 0; j < 8; ++j) bfrag.u[j] = f2bf(xv[j]);
        #pragma unroll
        for (int ot = 0; ot < 6; ++ot) {
            const int orow = (oh * 6 + ot) * 16 + pxl;
            union { float4 f; bf16x8 v; } afrag;
            afrag.f = *(const float4*)&wbf[orow * 256 + cbase];
            acc[ot] = __builtin_amdgcn_mfma_f32_16x16x32_bf16(afrag.v, bfrag.v, acc[ot], 0, 0, 0);
        }
    }

    s  += __shfl_xor(s, 16, 64);  s  += __shfl_xor(s, 32, 64);
    ss += __shfl_xor(ss, 16, 64); ss += __shfl_xor(ss, 32, 64);
    const float m = s * (1.f / 256.f);
    const float rsv = rsqrtf(ss * (1.f / 256.f) - m * m + 1e-5f);

    const int px = pt * 16 + pxl;
    #pragma unroll
    for (int ot = 0; ot < 6; ++ot) {
        #pragma unroll
        for (int r = 0; r < 4; ++r) {
            int o = (oh * 6 + ot) * 16 + quad * 4 + r;
            tile[px * 193 + o] = rsv * (acc[ot][r] - m * AB[o]) + AB[192 + o];
        }
    }
    __syncthreads();

    float*  qp  = ws + OFF_QP;
    __half* qth = (__half*)(ws + OFF_QT);
    __half* kvh = (__half*)(ws + OFF_KT);
    const int colrow = row * 64;
    #pragma unroll
    for (int it = 0; it < 8; ++it) {
        int idx = it * 512 + t;
        int o = idx >> 6, px2 = idx & 63;
        qp[(size_t)(b * 64 + o) * HW + colrow + px2] = tile[px2 * 193 + o];
    }
    #pragma unroll
    for (int it = 0; it < 8; ++it) {
        int idx = it * 512 + t;
        int px2 = idx >> 6, o = idx & 63;
        qth[(size_t)(b * HW + colrow + px2) * 64 + o] = __float2half(tile[px2 * 193 + o]);
    }
    #pragma unroll
    for (int it = 0; it < 4; ++it) {
        int idx = it * 512 + t;
        int px2 = idx >> 5, ch32 = idx & 31;
        int sB = ch32 >> 4, ch = ch32 & 15;
        kvh[(size_t)((2 * b) * HW + colrow + px2) * 64 + sB * 32 + ch]
            = __float2half(tile[px2 * 193 + 64 + ch32]);
    }
    #pragma unroll
    for (int it = 0; it < 4; ++it) {
        int idx = it * 512 + t;
        int px2 = idx >> 5, ch32 = idx & 31;
        int sB = ch32 >> 4, ch = ch32 & 15;
        kvh[(size_t)((2 * b + 1) * HW + colrow + px2) * 64 + sB * 32 + ch]
            = __float2half(tile[px2 * 193 + 96 + ch32]);
    }
    #pragma unroll
    for (int it = 0; it < 4; ++it) {
        int idx = it * 512 + t;
        int px2 = idx >> 5, ch32 = idx & 31;
        int sB = ch32 >> 4, ch = ch32 & 15;
        kvh[(size_t)((2 * b) * HW + colrow + px2) * 64 + sB * 32 + 16 + ch]
            = __float2half(tile[px2 * 193 + 128 + ch32]);
    }
    #pragma unroll
    for (int it = 0; it < 4; ++it) {
        int idx = it * 512 + t;
        int px2 = idx >> 5, ch32 = idx & 31;
        int sB = ch32 >> 4, ch = ch32 & 15;
        kvh[(size_t)((2 * b + 1) * HW + colrow + px2) * 64 + sB * 32 + 16 + ch]
            = __float2half(tile[px2 * 193 + 160 + ch32]);
    }
}

// ------- k23: FUSED depthwise3x3+LN+GELU (3 rows, LDS) -> conv 32->18 + tanh -------
// grid 1024 (bg = blk>>6, row = blk&63), block 256 = 4 waves.
// LDS: q5 [5][32][64] (40KB, reused as part[72][64] later) + t3 [3][32][64] (24KB)
//      + reductions (~2.5KB) = ~66.5KB -> 2 blocks/CU.
__global__ __launch_bounds__(256) void k23_fused(
    const float* __restrict__ wdw, const float* __restrict__ g2, const float* __restrict__ b2,
    const float* __restrict__ boff, const float* __restrict__ off_in,
    float* __restrict__ ws)
{
    __shared__ float smem[5 * 32 * 64 + 3 * 32 * 64 + 4 * 64 + 4 * 64 + 64 + 64];
    float* q5   = smem;                       // [5][32][64]; later reused as part[72][64]
    float* t3   = smem + 5 * 32 * 64;         // [3][32][64]
    float* rsum = smem + 8 * 32 * 64;         // [4][64]
    float* rsq  = rsum + 4 * 64;              // [4][64]
    float* smv  = rsq + 4 * 64;               // [64]
    float* srv  = smv + 64;                   // [64]

    const int t = threadIdx.x;
    const int bg = blockIdx.x >> 6, row = blockIdx.x & 63;
    const int p = t & 63;
    const int cq = __builtin_amdgcn_readfirstlane(t >> 6);
    const int b = bg >> 1, g = bg & 1;
    const float* qp = ws + OFF_QP;

    // stage q rows row-2 .. row+2 (zero pad outside): 5*32*16 float4 = 2560
    #pragma unroll
    for (int it = 0; it < 10; ++it) {
        int idx = it * 256 + t;
        int rc = idx >> 4;                 // 0..159
        int seg = (idx & 15) << 2;
        int dyy = rc >> 5, ch = rc & 31;   // dyy 0..4
        int y = row + dyy - 2;
        float4 v = make_float4(0.f, 0.f, 0.f, 0.f);
        if ((unsigned)y < 64u)
            v = *(const float4*)&qp[(size_t)(b * 64 + g * 32 + ch) * HW + y * 64 + seg];
        *(float4*)&q5[(dyy * 32 + ch) * 64 + seg] = v;
    }
    __syncthreads();

    // t rows row-1 .. row+1 : depthwise 3x3 + LN(32) + GELU into LDS (zero rows outside)
    for (int rr = 0; rr < 3; ++rr) {
        const int y = row + rr - 1;
        const bool yv = ((unsigned)y < 64u);   // block-uniform
        float vals[8] = {0.f, 0.f, 0.f, 0.f, 0.f, 0.f, 0.f, 0.f};
        float s = 0.f, ssq = 0.f;
        if (yv) {
            #pragma unroll
            for (int i = 0; i < 8; ++i) {
                int ch = cq * 8 + i;
                float a = 0.f;
                #pragma unroll
                for (int dy = 0; dy < 3; ++dy) {
                    #pragma unroll
                    for (int dx = 0; dx < 3; ++dx) {
                        int xx = p + dx - 1;
                        bool vld = (unsigned)xx < 64u;
                        float q = q5[((rr + dy) * 32 + ch) * 64 + (vld ? xx : 0)];
                        a += (vld ? q : 0.f) * wdw[ch * 9 + dy * 3 + dx];
                    }
                }
                vals[i] = a; s += a; ssq += a * a;
            }
        }
        rsum[cq * 64 + p] = s; rsq[cq * 64 + p] = ssq;
        __syncthreads();
        if (t < 64) {
            float S = rsum[t] + rsum[64 + t] + rsum[128 + t] + rsum[192 + t];
            float Q = rsq[t] + rsq[64 + t] + rsq[128 + t] + rsq[192 + t];
            float m = S * (1.f / 32.f);
            float v = Q * (1.f / 32.f) - m * m;
            smv[t] = m; srv[t] = rsqrtf(v + 1e-5f);
        }
        __syncthreads();
        const float m = smv[p], rv = srv[p];
        #pragma unroll
        for (int i = 0; i < 8; ++i) {
            int ch = cq * 8 + i;
            float ge = 0.f;
            if (yv) {
                float u = (vals[i] - m) * rv * g2[ch] + b2[ch];
                ge = 0.5f * u * (1.f + erff(u * 0.70710678118654752f));
            }
            t3[(rr * 32 + ch) * 64 + p] = ge;
        }
        __syncthreads();
    }

    // conv 32->18 over t3 (ic split across the 4 waves)
    const float* wfT = ws + OFF_WFT;
    float acc[18];
    #pragma unroll
    for (int o = 0; o < 18; ++o) acc[o] = 0.f;
    #pragma unroll
    for (int dy = 0; dy < 3; ++dy) {
        #pragma unroll
        for (int dx = 0; dx < 3; ++dx) {
            int xx = p + dx - 1;
            bool vld = (unsigned)xx < 64u;
            int xc = vld ? xx : 0;
            int wo = dy * 3 + dx;
            #pragma unroll
            for (int i = 0; i < 8; ++i) {
                int ic = cq * 8 + i;
                float tv = t3[(dy * 32 + ic) * 64 + xc];
                tv = vld ? tv : 0.f;
                const float* wrow = wfT + (wo * 32 + ic) * 18;
                #pragma unroll
                for (int o = 0; o < 18; ++o)
                    acc[o] += tv * wrow[o];
            }
        }
    }
    float* part = q5;   // q5 region no longer needed (all reads happened pre-loop syncs)
    #pragma unroll
    for (int o = 0; o < 18; ++o) part[(cq * 18 + o) * 64 + p] = acc[o];
    __syncthreads();
    float* ob = ws + OFF_OFFB;
    #pragma unroll
    for (int r = 0; r < 5; ++r) {
        int idx = t + r * 256;
        if (idx < 1152) {
            int o = idx >> 6, p2 = idx & 63;
            float v = part[o * 64 + p2] + part[(18 + o) * 64 + p2]
                    + part[(36 + o) * 64 + p2] + part[(54 + o) * 64 + p2] + boff[o];
            v = tanhf(v) * 5.0f + off_in[(size_t)(b * 18 + o) * HW + row * 64 + p2];
            ob[(size_t)(bg * 18 + o) * HW + row * 64 + p2] = v;
        }
    }
}

// ---- k4: deformable gather + softmax attn, fp16 KV; ao out = bf16 pix-major ----
__global__ __launch_bounds__(256, 4) void k4_attn(
    const float* __restrict__ rpb, float* __restrict__ ws)
{
    __shared__ float rpb_l[NHD * NTAP * HC]; // 576 floats
    for (int i = threadIdx.x; i < NHD * NTAP * HC; i += 256) rpb_l[i] = rpb[i];
    __syncthreads();

    const int t = threadIdx.x;
    const int wave = __builtin_amdgcn_readfirstlane(t >> 6);
    const int g = wave & 1, pxh = wave >> 1;
    const int lane = t & 63;
    const int pxl = lane & 7;
    const int prt = lane >> 3;
    const int s    = prt >> 2;
    const int half = (prt >> 1) & 1;
    const int j    = prt & 1;
    const int b = blockIdx.x & 7;
    const int chunk = blockIdx.x >> 3;          // 0..255
    const int hw = chunk * 16 + pxh * 8 + pxl;
    const int pix = b * HW + hw;
    const int bg = b * 2 + g;
    const int head = g * 2 + s;

    const __half* qth = (const __half*)(ws + OFF_QT);
    const __half* kvh = (const __half*)(ws + OFF_KT);
    const float*  ob  = ws + OFF_OFFB;

    union F4H { float4 f; __half2 h[4]; };
    F4H qld;
    qld.f = *(const float4*)&qth[(size_t)pix * 64 + g * 32 + s * 16 + j * 8];
    const float qs = half ? 0.0f : 0.25f;
    float qv[8];
    #pragma unroll
    for (int i = 0; i < 4; ++i) {
        float2 q2 = __half22float2(qld.h[i]);
        qv[2 * i] = q2.x * qs; qv[2 * i + 1] = q2.y * qs;
    }

    const float4* rb4 = (const float4*)(rpb_l + head * (NTAP * HC) + j * 8);
    const __half* kvp = kvh + (size_t)(bg * HW) * 64 + prt * 8;

    __half2 av[NTAP][4];
    float logit[NTAP];

    #pragma unroll
    for (int n = 0; n < NTAP; ++n) {
        float r = ob[(size_t)(bg * 18 + 2 * n) * HW + hw];
        float c = ob[(size_t)(bg * 18 + 2 * n + 1) * HW + hw];
        float y0f = floorf(r), x0f = floorf(c);
        float fy = r - y0f, fx = c - x0f;
        int iy0 = (int)y0f, ix0 = (int)x0f;
        float wts[4] = { (1.f - fx) * (1.f - fy), fx * (1.f - fy),
                         (1.f - fx) * fy,         fx * fy };
        __half2 acc0 = __float2half2_rn(0.f), acc1 = acc0, acc2 = acc0, acc3 = acc0;
        #pragma unroll
        for (int corner = 0; corner < 4; ++corner) {
            int cxx = ix0 + (corner & 1);
            int cyy = iy0 + (corner >> 1);
            bool vld = ((unsigned)cxx < 64u) && ((unsigned)cyy < 64u);
            float w = vld ? wts[corner] : 0.f;
            int cxc = min(max(cxx, 0), 63);
            int cyc = min(max(cyy, 0), 63);
            F4H kv;
            kv.f = *(const float4*)&kvp[(size_t)(cyc * 64 + cxc) * 64];
            __half2 w2 = __float2half2_rn(w);
            acc0 = __hfma2(kv.h[0], w2, acc0);
            acc1 = __hfma2(kv.h[1], w2, acc1);
            acc2 = __hfma2(kv.h[2], w2, acc2);
            acc3 = __hfma2(kv.h[3], w2, acc3);
        }
        av[n][0] = acc0; av[n][1] = acc1; av[n][2] = acc2; av[n][3] = acc3;
        float4 r0 = rb4[n * 4], r1 = rb4[n * 4 + 1];
        float2 a0 = __half22float2(acc0), a1 = __half22float2(acc1);
        float2 a2 = __half22float2(acc2), a3 = __half22float2(acc3);
        float part = qv[0] * (a0.x + r0.x) + qv[1] * (a0.y + r0.y)
                   + qv[2] * (a1.x + r0.z) + qv[3] * (a1.y + r0.w)
                   + qv[4] * (a2.x + r1.x) + qv[5] * (a2.y + r1.y)
                   + qv[6] * (a3.x + r1.z) + qv[7] * (a3.y + r1.w);
        part += __shfl_xor(part, 8, 64);
        part += __shfl_xor(part, 16, 64);
        logit[n] = part;
    }

    float m = logit[0];
    #pragma unroll
    for (int n = 1; n < NTAP; ++n) m = fmaxf(m, logit[n]);
    float l = 0.f;
    #pragma unroll
    for (int n = 0; n < NTAP; ++n) { logit[n] = __expf(logit[n] - m); l += logit[n]; }
    const float inv = 1.f / l;

    __half2 o0 = __float2half2_rn(0.f), o1 = o0, o2 = o0, o3 = o0;
    #pragma unroll
    for (int n = 0; n < NTAP; ++n) {
        __half2 p2 = __float2half2_rn(logit[n]);
        o0 = __hfma2(av[n][0], p2, o0);
        o1 = __hfma2(av[n][1], p2, o1);
        o2 = __hfma2(av[n][2], p2, o2);
        o3 = __hfma2(av[n][3], p2, o3);
    }
    if (half) {   // v-lanes write ao bf16 pixel-major [pix][64]
        unsigned short* aob = (unsigned short*)(ws + OFF_AOT);
        const int cb = head * 16 + j * 8;
        float2 f0 = __half22float2(o0), f1 = __half22float2(o1);
        float2 f2 = __half22float2(o2), f3 = __half22float2(o3);
        union { float4 f; unsigned short u[8]; } pk;
        pk.u[0] = f2bf(f0.x * inv); pk.u[1] = f2bf(f0.y * inv);
        pk.u[2] = f2bf(f1.x * inv); pk.u[3] = f2bf(f1.y * inv);
        pk.u[4] = f2bf(f2.x * inv); pk.u[5] = f2bf(f2.y * inv);
        pk.u[6] = f2bf(f3.x * inv); pk.u[7] = f2bf(f3.y * inv);
        *(float4*)&aob[(size_t)pix * 64 + cb] = pk.f;
    }
}

// ---- k5: fused proj(64->256)+bias+residual -> cls(256->80), all bf16 MFMA ----
__global__ __launch_bounds__(256) void k5_mfma(
    const float* __restrict__ x, const float* __restrict__ bproj,
    const float* __restrict__ bcls, float* __restrict__ ws, float* __restrict__ out)
{
    __shared__ unsigned short tmp[64][264];   // bf16 [px][256 c] pad 8 -> 33.8 KB
    const int t = threadIdx.x;
    const int b = blockIdx.x & 7, row = blockIdx.x >> 3;
    const int wv = __builtin_amdgcn_readfirstlane(t >> 6);
    const int lane = t & 63, quad = lane >> 4, pxl = lane & 15;
    const int px = wv * 16 + pxl;
    const int pixcol = row * 64 + px;
    const size_t pix = (size_t)b * HW + pixcol;
    const unsigned short* aob = (const unsigned short*)(ws + OFF_AOT);
    const unsigned short* wpb = (const unsigned short*)(ws + OFF_WPT);
    const unsigned short* wcb = (const unsigned short*)(ws + OFF_WCT);

    union FB { float4 f; bf16x8 v; };
    FB bf0, bf1;
    bf0.f = *(const float4*)&aob[pix * 64 + quad * 8];
    bf1.f = *(const float4*)&aob[pix * 64 + 32 + quad * 8];

    // proj: 16 o-tiles of 16; k = 64 (2 MFMA)
    #pragma unroll 4
    for (int ot = 0; ot < 16; ++ot) {
        f32x4 acc = (f32x4){0.f, 0.f, 0.f, 0.f};
        FB a0, a1;
        const int om = ot * 16 + pxl;
        a0.f = *(const float4*)&wpb[om * 64 + quad * 8];
        a1.f = *(const float4*)&wpb[om * 64 + 32 + quad * 8];
        acc = __builtin_amdgcn_mfma_f32_16x16x32_bf16(a0.v, bf0.v, acc, 0, 0, 0);
        acc = __builtin_amdgcn_mfma_f32_16x16x32_bf16(a1.v, bf1.v, acc, 0, 0, 0);
        union { unsigned short u[4]; ushort2 s2[2]; } pk;
        #pragma unroll
        for (int r = 0; r < 4; ++r) {
            int o = ot * 16 + quad * 4 + r;
            float v = acc[r] + bproj[o] + x[(size_t)(b * DIM + o) * HW + pixcol];
            pk.u[r] = f2bf(v);
        }
        *(ushort4*)&tmp[px][ot * 16 + quad * 4] = *(ushort4*)pk.u;
    }
    __syncthreads();

    // cls: 5 oc-tiles of 16; k = 256 (8 chunks)
    f32x4 acc2[5];
    #pragma unroll
    for (int oc = 0; oc < 5; ++oc) acc2[oc] = (f32x4){0.f, 0.f, 0.f, 0.f};
    #pragma unroll
    for (int kc = 0; kc < 8; ++kc) {
        FB bb;
        bb.f = *(const float4*)&tmp[px][kc * 32 + quad * 8];
        #pragma unroll
        for (int oc = 0; oc < 5; ++oc) {
            FB aa;
            aa.f = *(const float4*)&wcb[(oc * 16 + pxl) * 256 + kc * 32 + quad * 8];
            acc2[oc] = __builtin_amdgcn_mfma_f32_16x16x32_bf16(aa.v, bb.v, acc2[oc], 0, 0, 0);
        }
    }
    #pragma unroll
    for (int oc = 0; oc < 5; ++oc) {
        #pragma unroll
        for (int r = 0; r < 4; ++r) {
            int o = oc * 16 + quad * 4 + r;
            out[(size_t)(b * NCLS + o) * HW + pixcol] = acc2[oc][r] + bcls[o];
        }
    }
}

extern "C" void kernel_launch(void* const* d_in, const int* in_sizes, int n_in,
                              void* d_out, int out_size, void* d_ws, size_t ws_size,
                              hipStream_t stream)
{
    const float* x     = (const float*)d_in[0];
    const float* off   = (const float*)d_in[1];
    const float* g1    = (const float*)d_in[2];
    const float* b1    = (const float*)d_in[3];
    const float* wqkv  = (const float*)d_in[4];
    const float* wdw   = (const float*)d_in[5];
    const float* g2    = (const float*)d_in[6];
    const float* b2    = (const float*)d_in[7];
    const float* woff  = (const float*)d_in[8];
    const float* boff  = (const float*)d_in[9];
    const float* rpb   = (const float*)d_in[10];
    const float* wproj = (const float*)d_in[11];
    const float* bproj = (const float*)d_in[12];
    const float* wcls  = (const float*)d_in[13];
    const float* bcls  = (const float*)d_in[14];
    float* ws  = (float*)d_ws;
    float* out = (float*)d_out;

    hipLaunchKernelGGL(k0_prep,   dim3(449),  dim3(256), 0, stream, wqkv, g1, b1, woff, wproj, wcls, ws);
    hipLaunchKernelGGL(k1_mfma,   dim3(512),  dim3(512), 0, stream, x, ws);
    hipLaunchKernelGGL(k23_fused, dim3(1024), dim3(256), 0, stream, wdw, g2, b2, boff, off, ws);
    hipLaunchKernelGGL(k4_attn,   dim3(2048), dim3(256), 0, stream, rpb, ws);
    hipLaunchKernelGGL(k5_mfma,   dim3(512),  dim3(256), 0, stream, x, bproj, bcls, ws, out);
}

// Round 2
// 238.977 us; speedup vs baseline: 1.0888x; 1.0888x over previous
//
#include <hip/hip_runtime.h>
#include <hip/hip_fp16.h>
#include <math.h>

// Problem constants
#define BB   8
#define HW   4096
#define BHW  32768
#define DIM  256
#define CR   64
#define GC   32
#define NHD  4
#define HC   16
#define NTAP 9
#define NCLS 80

// workspace layout (float offsets)
#define OFF_QP   0u          // q planar   [B][64][H][W] fp32       2,097,152
#define OFF_QT   2097152u    // q pix-major[B*HW][64] fp16          1,048,576 (floats of space)
#define OFF_KT   4194304u    // KV fp16 [BG][HW][2 sub][k16|v16]    2,097,152 (floats of space)
#define OFF_T    8388608u    // t planar   [BG][32][H][W]           2,097,152
// --- overlap region: inside OFF_T's span; k0 writes each call, k1 reads,
//     then k2 clobbers with T (k1 already done) ---
#define OFF_WBF  8388608u    // W_qkv·g1 bf16 [192][256]            24,576 float-slots
#define OFF_AB   8437760u    // A[192], B[192]                      384
// ------------------------------------------------------------------------
#define OFF_OFFB 10485760u   // off planar [BG][18][H][W]           1,179,648
#define OFF_AOT  11665408u   // attn out bf16 [B*HW][64] pix-major  1,048,576 float-slots used
#define OFF_WPT  13762560u   // wproj bf16 [256][64]                8,192 float-slots used
#define OFF_WCT  13778944u   // wcls  bf16 [80][256]                10,240 float-slots used
#define OFF_WFT  13799424u   // woff^T  [9][32][18]                 5,184

typedef short bf16x8 __attribute__((ext_vector_type(8)));
typedef float f32x4  __attribute__((ext_vector_type(4)));

__device__ __forceinline__ unsigned short f2bf(float f) {
    unsigned u = __float_as_uint(f);
    unsigned r = u + 0x7FFFu + ((u >> 16) & 1u);   // round-to-nearest-even
    return (unsigned short)(r >> 16);
}

// ---------------- k0: weight prep ----------------
__global__ __launch_bounds__(256) void k0_prep(
    const float* __restrict__ wqkv, const float* __restrict__ g1,
    const float* __restrict__ b1, const float* __restrict__ woff,
    const float* __restrict__ wproj, const float* __restrict__ wcls,
    float* __restrict__ ws)
{
    const int t = threadIdx.x;
    const int blk = blockIdx.x;
    if (blk < 192) {
        const int o = blk;
        unsigned short* wbf = (unsigned short*)(ws + OFF_WBF);
        wbf[o * 256 + t] = f2bf(wqkv[o * 256 + t] * g1[t]);
    } else if (blk < 448) {
        const int r = blk - 192;   // 0..255
        unsigned short* wpb = (unsigned short*)(ws + OFF_WPT);
        unsigned short* wcb = (unsigned short*)(ws + OFF_WCT);
        if (t < 64) wpb[r * 64 + t] = f2bf(wproj[r * 64 + t]);
        if (r < 80) wcb[r * 256 + t] = f2bf(wcls[r * 256 + t]);
    } else {
        if (t < 192) {
            float a = 0.f, bb = 0.f;
            for (int c = 0; c < 256; ++c) {
                float w = wqkv[t * 256 + c];
                a += w * g1[c]; bb += w * b1[c];
            }
            ws[OFF_AB + t] = a;
            ws[OFF_AB + 192 + t] = bb;
            for (int pair = t; pair < 288; pair += 192) {
                int wo = pair >> 5, ic = pair & 31;
                for (int o = 0; o < 18; ++o)
                    ws[OFF_WFT + (wo * 32 + ic) * 18 + o] = woff[(o * 32 + ic) * 9 + wo];
            }
        }
    }
}

// ------ k1: QKV GEMM via bf16 MFMA, LN folded in epilogue, fp16 q/KV out ------
// grid 512 (b = blk&7 XCD-affine, row = blk>>3), block 512 = 8 waves.
__global__ __launch_bounds__(512) void k1_mfma(
    const float* __restrict__ x, float* __restrict__ ws)
{
    __shared__ float tile[64 * 193];   // 49.4 KB transpose tile [px][o] pad 193
    const int t = threadIdx.x;
    const int b = blockIdx.x & 7, row = blockIdx.x >> 3;
    const int wv = __builtin_amdgcn_readfirstlane(t >> 6);
    const int pt = wv & 3, oh = wv >> 2;
    const int lane = t & 63;
    const int quad = lane >> 4, pxl = lane & 15;
    const int colbase = row * 64 + pt * 16 + pxl;
    const unsigned short* wbf = (const unsigned short*)(ws + OFF_WBF);
    const float* AB = ws + OFF_AB;

    f32x4 acc[6];
    #pragma unroll
    for (int ot = 0; ot < 6; ++ot) acc[ot] = (f32x4){0.f, 0.f, 0.f, 0.f};
    float s = 0.f, ss = 0.f;
    const size_t xb0 = (size_t)b * DIM * HW + colbase;

    for (int ks = 0; ks < 8; ++ks) {
        const int cbase = ks * 32 + quad * 8;
        float xv[8];
        #pragma unroll
        for (int j = 0; j < 8; ++j) {
            xv[j] = x[xb0 + (size_t)(cbase + j) * HW];
            s += xv[j]; ss += xv[j] * xv[j];
        }
        union { bf16x8 v; unsigned short u[8]; } bfrag;
        #pragma unroll
        for (int j = 0; j < 8; ++j) bfrag.u[j] = f2bf(xv[j]);
        #pragma unroll
        for (int ot = 0; ot < 6; ++ot) {
            const int orow = (oh * 6 + ot) * 16 + pxl;
            union { float4 f; bf16x8 v; } afrag;
            afrag.f = *(const float4*)&wbf[orow * 256 + cbase];
            acc[ot] = __builtin_amdgcn_mfma_f32_16x16x32_bf16(afrag.v, bfrag.v, acc[ot], 0, 0, 0);
        }
    }

    s  += __shfl_xor(s, 16, 64);  s  += __shfl_xor(s, 32, 64);
    ss += __shfl_xor(ss, 16, 64); ss += __shfl_xor(ss, 32, 64);
    const float m = s * (1.f / 256.f);
    const float rsv = rsqrtf(ss * (1.f / 256.f) - m * m + 1e-5f);

    const int px = pt * 16 + pxl;
    #pragma unroll
    for (int ot = 0; ot < 6; ++ot) {
        #pragma unroll
        for (int r = 0; r < 4; ++r) {
            int o = (oh * 6 + ot) * 16 + quad * 4 + r;
            tile[px * 193 + o] = rsv * (acc[ot][r] - m * AB[o]) + AB[192 + o];
        }
    }
    __syncthreads();

    float*  qp  = ws + OFF_QP;
    __half* qth = (__half*)(ws + OFF_QT);
    __half* kvh = (__half*)(ws + OFF_KT);
    const int colrow = row * 64;
    #pragma unroll
    for (int it = 0; it < 8; ++it) {
        int idx = it * 512 + t;
        int o = idx >> 6, px2 = idx & 63;
        qp[(size_t)(b * 64 + o) * HW + colrow + px2] = tile[px2 * 193 + o];
    }
    #pragma unroll
    for (int it = 0; it < 8; ++it) {
        int idx = it * 512 + t;
        int px2 = idx >> 6, o = idx & 63;
        qth[(size_t)(b * HW + colrow + px2) * 64 + o] = __float2half(tile[px2 * 193 + o]);
    }
    #pragma unroll
    for (int it = 0; it < 4; ++it) {
        int idx = it * 512 + t;
        int px2 = idx >> 5, ch32 = idx & 31;
        int sB = ch32 >> 4, ch = ch32 & 15;
        kvh[(size_t)((2 * b) * HW + colrow + px2) * 64 + sB * 32 + ch]
            = __float2half(tile[px2 * 193 + 64 + ch32]);
    }
    #pragma unroll
    for (int it = 0; it < 4; ++it) {
        int idx = it * 512 + t;
        int px2 = idx >> 5, ch32 = idx & 31;
        int sB = ch32 >> 4, ch = ch32 & 15;
        kvh[(size_t)((2 * b + 1) * HW + colrow + px2) * 64 + sB * 32 + ch]
            = __float2half(tile[px2 * 193 + 96 + ch32]);
    }
    #pragma unroll
    for (int it = 0; it < 4; ++it) {
        int idx = it * 512 + t;
        int px2 = idx >> 5, ch32 = idx & 31;
        int sB = ch32 >> 4, ch = ch32 & 15;
        kvh[(size_t)((2 * b) * HW + colrow + px2) * 64 + sB * 32 + 16 + ch]
            = __float2half(tile[px2 * 193 + 128 + ch32]);
    }
    #pragma unroll
    for (int it = 0; it < 4; ++it) {
        int idx = it * 512 + t;
        int px2 = idx >> 5, ch32 = idx & 31;
        int sB = ch32 >> 4, ch = ch32 & 15;
        kvh[(size_t)((2 * b + 1) * HW + colrow + px2) * 64 + sB * 32 + 16 + ch]
            = __float2half(tile[px2 * 193 + 160 + ch32]);
    }
}

// ------- k2: depthwise 3x3 + LN(32) + GELU; q rows staged in LDS -------
// XCD-affine mapping: b = blk&7 (matches k1's qp[b] producer XCD), g=(blk>>3)&1,
// row = blk>>4. Per-XCD qp slice = 1 MB, t slice = 1 MB -> L2-resident.
__global__ __launch_bounds__(256) void k2_off_feat(
    const float* __restrict__ wdw, const float* __restrict__ g2, const float* __restrict__ b2,
    float* __restrict__ ws)
{
    __shared__ float qtile[3][32][64];              // 24 KB
    __shared__ float rsum[4][64], rsq[4][64], smv[64], srv[64];
    const int t = threadIdx.x;
    const int b = blockIdx.x & 7;
    const int rest = blockIdx.x >> 3;
    const int g = rest & 1;
    const int row = rest >> 1;
    const int bg = b * 2 + g;
    const int p = t & 63;
    const int cq = __builtin_amdgcn_readfirstlane(t >> 6);
    const float* qp = ws + OFF_QP;

    #pragma unroll
    for (int it = 0; it < 6; ++it) {
        int idx = it * 256 + t;
        int rc = idx >> 4;
        int seg = (idx & 15) << 2;
        int dyy = rc >> 5, ch = rc & 31;
        int y = row + dyy - 1;
        float4 v = make_float4(0.f, 0.f, 0.f, 0.f);
        if ((unsigned)y < 64u)
            v = *(const float4*)&qp[(size_t)(b * 64 + g * 32 + ch) * HW + y * 64 + seg];
        *(float4*)&qtile[dyy][ch][seg] = v;
    }
    __syncthreads();

    float vals[8];
    float s = 0.f, ss = 0.f;
    #pragma unroll
    for (int i = 0; i < 8; ++i) {
        int ch = cq * 8 + i;
        float a = 0.f;
        #pragma unroll
        for (int dy = 0; dy < 3; ++dy) {
            #pragma unroll
            for (int dx = 0; dx < 3; ++dx) {
                int xx = p + dx - 1;
                bool vld = (unsigned)xx < 64u;
                float q = qtile[dy][ch][vld ? xx : 0];
                a += (vld ? q : 0.f) * wdw[ch * 9 + dy * 3 + dx];
            }
        }
        vals[i] = a; s += a; ss += a * a;
    }
    rsum[cq][p] = s; rsq[cq][p] = ss;
    __syncthreads();
    if (t < 64) {
        float S = rsum[0][t] + rsum[1][t] + rsum[2][t] + rsum[3][t];
        float Q = rsq[0][t] + rsq[1][t] + rsq[2][t] + rsq[3][t];
        float m = S * (1.f / 32.f);
        float v = Q * (1.f / 32.f) - m * m;
        smv[t] = m; srv[t] = rsqrtf(v + 1e-5f);
    }
    __syncthreads();
    float m = smv[p], rv = srv[p];
    float* tb = ws + OFF_T;
    #pragma unroll
    for (int i = 0; i < 8; ++i) {
        int ch = cq * 8 + i;
        float u = (vals[i] - m) * rv * g2[ch] + b2[ch];
        float ge = 0.5f * u * (1.f + erff(u * 0.70710678118654752f));
        tb[(size_t)(bg * 32 + ch) * HW + row * 64 + p] = ge;
    }
}

// ------- k3: 3x3 conv 32->18 + tanh*5 + base offset, ic-split across waves -------
// Same XCD-affine mapping as k2: t[bg] and ob[bg] stay in the producing XCD's L2.
__global__ __launch_bounds__(256) void k3_pred_off(
    const float* __restrict__ boff, const float* __restrict__ off_in,
    float* __restrict__ ws)
{
    __shared__ float part[4 * 18 * 64];
    const int t = threadIdx.x;
    const int b = blockIdx.x & 7;
    const int rest = blockIdx.x >> 3;
    const int g = rest & 1;
    const int row = rest >> 1;
    const int bg = b * 2 + g;
    const int p = t & 63;
    const int icq = __builtin_amdgcn_readfirstlane(t >> 6);
    const float* tb = ws + OFF_T;
    const float* wfT = ws + OFF_WFT;
    float acc[18];
    #pragma unroll
    for (int o = 0; o < 18; ++o) acc[o] = 0.f;
    #pragma unroll
    for (int dy = 0; dy < 3; ++dy) {
        int y = row + dy - 1;
        if ((unsigned)y >= 64u) continue;
        #pragma unroll
        for (int dx = 0; dx < 3; ++dx) {
            int xx = p + dx - 1;
            bool vld = (unsigned)xx < 64u;
            int xc = vld ? xx : 0;
            int wo = dy * 3 + dx;
            #pragma unroll
            for (int i = 0; i < 8; ++i) {
                int ic = icq * 8 + i;
                float tv = tb[(size_t)(bg * 32 + ic) * HW + y * 64 + xc];
                tv = vld ? tv : 0.f;
                const float* wrow = wfT + (wo * 32 + ic) * 18;
                #pragma unroll
                for (int o = 0; o < 18; ++o)
                    acc[o] += tv * wrow[o];
            }
        }
    }
    #pragma unroll
    for (int o = 0; o < 18; ++o) part[(icq * 18 + o) * 64 + p] = acc[o];
    __syncthreads();
    float* ob = ws + OFF_OFFB;
    #pragma unroll
    for (int r = 0; r < 5; ++r) {
        int idx = t + r * 256;
        if (idx < 1152) {
            int o = idx >> 6, p2 = idx & 63;
            float v = part[o * 64 + p2] + part[(18 + o) * 64 + p2]
                    + part[(36 + o) * 64 + p2] + part[(54 + o) * 64 + p2] + boff[o];
            v = tanhf(v) * 5.0f + off_in[(size_t)(b * 18 + o) * HW + row * 64 + p2];
            ob[(size_t)(bg * 18 + o) * HW + row * 64 + p2] = v;
        }
    }
}

// ---- k4: deformable gather + softmax attn, fp16 KV; ao out = bf16 pix-major ----
__global__ __launch_bounds__(256, 4) void k4_attn(
    const float* __restrict__ rpb, float* __restrict__ ws)
{
    __shared__ float rpb_l[NHD * NTAP * HC]; // 576 floats
    for (int i = threadIdx.x; i < NHD * NTAP * HC; i += 256) rpb_l[i] = rpb[i];
    __syncthreads();

    const int t = threadIdx.x;
    const int wave = __builtin_amdgcn_readfirstlane(t >> 6);
    const int g = wave & 1, pxh = wave >> 1;
    const int lane = t & 63;
    const int pxl = lane & 7;
    const int prt = lane >> 3;
    const int s    = prt >> 2;
    const int half = (prt >> 1) & 1;
    const int j    = prt & 1;
    const int b = blockIdx.x & 7;
    const int chunk = blockIdx.x >> 3;          // 0..255
    const int hw = chunk * 16 + pxh * 8 + pxl;
    const int pix = b * HW + hw;
    const int bg = b * 2 + g;
    const int head = g * 2 + s;

    const __half* qth = (const __half*)(ws + OFF_QT);
    const __half* kvh = (const __half*)(ws + OFF_KT);
    const float*  ob  = ws + OFF_OFFB;

    union F4H { float4 f; __half2 h[4]; };
    F4H qld;
    qld.f = *(const float4*)&qth[(size_t)pix * 64 + g * 32 + s * 16 + j * 8];
    const float qs = half ? 0.0f : 0.25f;
    float qv[8];
    #pragma unroll
    for (int i = 0; i < 4; ++i) {
        float2 q2 = __half22float2(qld.h[i]);
        qv[2 * i] = q2.x * qs; qv[2 * i + 1] = q2.y * qs;
    }

    const float4* rb4 = (const float4*)(rpb_l + head * (NTAP * HC) + j * 8);
    const __half* kvp = kvh + (size_t)(bg * HW) * 64 + prt * 8;

    __half2 av[NTAP][4];
    float logit[NTAP];

    #pragma unroll
    for (int n = 0; n < NTAP; ++n) {
        float r = ob[(size_t)(bg * 18 + 2 * n) * HW + hw];
        float c = ob[(size_t)(bg * 18 + 2 * n + 1) * HW + hw];
        float y0f = floorf(r), x0f = floorf(c);
        float fy = r - y0f, fx = c - x0f;
        int iy0 = (int)y0f, ix0 = (int)x0f;
        float wts[4] = { (1.f - fx) * (1.f - fy), fx * (1.f - fy),
                         (1.f - fx) * fy,         fx * fy };
        __half2 acc0 = __float2half2_rn(0.f), acc1 = acc0, acc2 = acc0, acc3 = acc0;
        #pragma unroll
        for (int corner = 0; corner < 4; ++corner) {
            int cxx = ix0 + (corner & 1);
            int cyy = iy0 + (corner >> 1);
            bool vld = ((unsigned)cxx < 64u) && ((unsigned)cyy < 64u);
            float w = vld ? wts[corner] : 0.f;
            int cxc = min(max(cxx, 0), 63);
            int cyc = min(max(cyy, 0), 63);
            F4H kv;
            kv.f = *(const float4*)&kvp[(size_t)(cyc * 64 + cxc) * 64];
            __half2 w2 = __float2half2_rn(w);
            acc0 = __hfma2(kv.h[0], w2, acc0);
            acc1 = __hfma2(kv.h[1], w2, acc1);
            acc2 = __hfma2(kv.h[2], w2, acc2);
            acc3 = __hfma2(kv.h[3], w2, acc3);
        }
        av[n][0] = acc0; av[n][1] = acc1; av[n][2] = acc2; av[n][3] = acc3;
        float4 r0 = rb4[n * 4], r1 = rb4[n * 4 + 1];
        float2 a0 = __half22float2(acc0), a1 = __half22float2(acc1);
        float2 a2 = __half22float2(acc2), a3 = __half22float2(acc3);
        float part = qv[0] * (a0.x + r0.x) + qv[1] * (a0.y + r0.y)
                   + qv[2] * (a1.x + r0.z) + qv[3] * (a1.y + r0.w)
                   + qv[4] * (a2.x + r1.x) + qv[5] * (a2.y + r1.y)
                   + qv[6] * (a3.x + r1.z) + qv[7] * (a3.y + r1.w);
        part += __shfl_xor(part, 8, 64);
        part += __shfl_xor(part, 16, 64);
        logit[n] = part;
    }

    float m = logit[0];
    #pragma unroll
    for (int n = 1; n < NTAP; ++n) m = fmaxf(m, logit[n]);
    float l = 0.f;
    #pragma unroll
    for (int n = 0; n < NTAP; ++n) { logit[n] = __expf(logit[n] - m); l += logit[n]; }
    const float inv = 1.f / l;

    __half2 o0 = __float2half2_rn(0.f), o1 = o0, o2 = o0, o3 = o0;
    #pragma unroll
    for (int n = 0; n < NTAP; ++n) {
        __half2 p2 = __float2half2_rn(logit[n]);
        o0 = __hfma2(av[n][0], p2, o0);
        o1 = __hfma2(av[n][1], p2, o1);
        o2 = __hfma2(av[n][2], p2, o2);
        o3 = __hfma2(av[n][3], p2, o3);
    }
    if (half) {   // v-lanes write ao bf16 pixel-major [pix][64]
        unsigned short* aob = (unsigned short*)(ws + OFF_AOT);
        const int cb = head * 16 + j * 8;
        float2 f0 = __half22float2(o0), f1 = __half22float2(o1);
        float2 f2 = __half22float2(o2), f3 = __half22float2(o3);
        union { float4 f; unsigned short u[8]; } pk;
        pk.u[0] = f2bf(f0.x * inv); pk.u[1] = f2bf(f0.y * inv);
        pk.u[2] = f2bf(f1.x * inv); pk.u[3] = f2bf(f1.y * inv);
        pk.u[4] = f2bf(f2.x * inv); pk.u[5] = f2bf(f2.y * inv);
        pk.u[6] = f2bf(f3.x * inv); pk.u[7] = f2bf(f3.y * inv);
        *(float4*)&aob[(size_t)pix * 64 + cb] = pk.f;
    }
}

// ---- k5: fused proj(64->256)+bias+residual -> cls(256->80), all bf16 MFMA ----
__global__ __launch_bounds__(256) void k5_mfma(
    const float* __restrict__ x, const float* __restrict__ bproj,
    const float* __restrict__ bcls, float* __restrict__ ws, float* __restrict__ out)
{
    __shared__ unsigned short tmp[64][264];   // bf16 [px][256 c] pad 8 -> 33.8 KB
    const int t = threadIdx.x;
    const int b = blockIdx.x & 7, row = blockIdx.x >> 3;
    const int wv = __builtin_amdgcn_readfirstlane(t >> 6);
    const int lane = t & 63, quad = lane >> 4, pxl = lane & 15;
    const int px = wv * 16 + pxl;
    const int pixcol = row * 64 + px;
    const size_t pix = (size_t)b * HW + pixcol;
    const unsigned short* aob = (const unsigned short*)(ws + OFF_AOT);
    const unsigned short* wpb = (const unsigned short*)(ws + OFF_WPT);
    const unsigned short* wcb = (const unsigned short*)(ws + OFF_WCT);

    union FB { float4 f; bf16x8 v; };
    FB bf0, bf1;
    bf0.f = *(const float4*)&aob[pix * 64 + quad * 8];
    bf1.f = *(const float4*)&aob[pix * 64 + 32 + quad * 8];

    // proj: 16 o-tiles of 16; k = 64 (2 MFMA)
    #pragma unroll 4
    for (int ot = 0; ot < 16; ++ot) {
        f32x4 acc = (f32x4){0.f, 0.f, 0.f, 0.f};
        FB a0, a1;
        const int om = ot * 16 + pxl;
        a0.f = *(const float4*)&wpb[om * 64 + quad * 8];
        a1.f = *(const float4*)&wpb[om * 64 + 32 + quad * 8];
        acc = __builtin_amdgcn_mfma_f32_16x16x32_bf16(a0.v, bf0.v, acc, 0, 0, 0);
        acc = __builtin_amdgcn_mfma_f32_16x16x32_bf16(a1.v, bf1.v, acc, 0, 0, 0);
        union { unsigned short u[4]; ushort2 s2[2]; } pk;
        #pragma unroll
        for (int r = 0; r < 4; ++r) {
            int o = ot * 16 + quad * 4 + r;
            float v = acc[r] + bproj[o] + x[(size_t)(b * DIM + o) * HW + pixcol];
            pk.u[r] = f2bf(v);
        }
        *(ushort4*)&tmp[px][ot * 16 + quad * 4] = *(ushort4*)pk.u;
    }
    __syncthreads();

    // cls: 5 oc-tiles of 16; k = 256 (8 chunks)
    f32x4 acc2[5];
    #pragma unroll
    for (int oc = 0; oc < 5; ++oc) acc2[oc] = (f32x4){0.f, 0.f, 0.f, 0.f};
    #pragma unroll
    for (int kc = 0; kc < 8; ++kc) {
        FB bb;
        bb.f = *(const float4*)&tmp[px][kc * 32 + quad * 8];
        #pragma unroll
        for (int oc = 0; oc < 5; ++oc) {
            FB aa;
            aa.f = *(const float4*)&wcb[(oc * 16 + pxl) * 256 + kc * 32 + quad * 8];
            acc2[oc] = __builtin_amdgcn_mfma_f32_16x16x32_bf16(aa.v, bb.v, acc2[oc], 0, 0, 0);
        }
    }
    #pragma unroll
    for (int oc = 0; oc < 5; ++oc) {
        #pragma unroll
        for (int r = 0; r < 4; ++r) {
            int o = oc * 16 + quad * 4 + r;
            out[(size_t)(b * NCLS + o) * HW + pixcol] = acc2[oc][r] + bcls[o];
        }
    }
}

extern "C" void kernel_launch(void* const* d_in, const int* in_sizes, int n_in,
                              void* d_out, int out_size, void* d_ws, size_t ws_size,
                              hipStream_t stream)
{
    const float* x     = (const float*)d_in[0];
    const float* off   = (const float*)d_in[1];
    const float* g1    = (const float*)d_in[2];
    const float* b1    = (const float*)d_in[3];
    const float* wqkv  = (const float*)d_in[4];
    const float* wdw   = (const float*)d_in[5];
    const float* g2    = (const float*)d_in[6];
    const float* b2    = (const float*)d_in[7];
    const float* woff  = (const float*)d_in[8];
    const float* boff  = (const float*)d_in[9];
    const float* rpb   = (const float*)d_in[10];
    const float* wproj = (const float*)d_in[11];
    const float* bproj = (const float*)d_in[12];
    const float* wcls  = (const float*)d_in[13];
    const float* bcls  = (const float*)d_in[14];
    float* ws  = (float*)d_ws;
    float* out = (float*)d_out;

    hipLaunchKernelGGL(k0_prep,     dim3(449),  dim3(256), 0, stream, wqkv, g1, b1, woff, wproj, wcls, ws);
    hipLaunchKernelGGL(k1_mfma,     dim3(512),  dim3(512), 0, stream, x, ws);
    hipLaunchKernelGGL(k2_off_feat, dim3(1024), dim3(256), 0, stream, wdw, g2, b2, ws);
    hipLaunchKernelGGL(k3_pred_off, dim3(1024), dim3(256), 0, stream, boff, off, ws);
    hipLaunchKernelGGL(k4_attn,     dim3(2048), dim3(256), 0, stream, rpb, ws);
    hipLaunchKernelGGL(k5_mfma,     dim3(512),  dim3(256), 0, stream, x, bproj, bcls, ws, out);
}

// Round 3
// 231.314 us; speedup vs baseline: 1.1249x; 1.0331x over previous
//
#include <hip/hip_runtime.h>
#include <hip/hip_fp16.h>
#include <math.h>

// Problem constants
#define BB   8
#define HW   4096
#define BHW  32768
#define DIM  256
#define CR   64
#define GC   32
#define NHD  4
#define HC   16
#define NTAP 9
#define NCLS 80

// workspace layout (float offsets)
#define OFF_QP   0u          // q planar   [B][64][H][W] fp32       2,097,152
#define OFF_QT   2097152u    // q pix-major[B*HW][64] fp16          1,048,576 (floats of space)
#define OFF_KT   4194304u    // KV fp16 [BG][HW][2 sub][k16|v16]    2,097,152 (floats of space)
#define OFF_T    8388608u    // t planar   [BG][32][H][W]           2,097,152
// --- overlap region: inside OFF_T's span; k0 writes each call, k1 reads,
//     then k2 clobbers with T (k1 already done) ---
#define OFF_WBF  8388608u    // W_qkv·g1 bf16 [192][256]            24,576 float-slots
#define OFF_AB   8437760u    // A[192], B[192]                      384
// ------------------------------------------------------------------------
#define OFF_OFFB 10485760u   // off planar [BG][18][H][W]           1,179,648
#define OFF_AOT  11665408u   // attn out bf16 [B*HW][64] pix-major  1,048,576 float-slots used
#define OFF_WPT  13762560u   // wproj bf16 [256][64]                8,192 float-slots used
#define OFF_WCT  13778944u   // wcls  bf16 [80][256]                10,240 float-slots used
#define OFF_WFT  13799424u   // woff^T  [9][32][18]                 5,184

typedef short bf16x8 __attribute__((ext_vector_type(8)));
typedef float f32x4  __attribute__((ext_vector_type(4)));

__device__ __forceinline__ unsigned short f2bf(float f) {
    unsigned u = __float_as_uint(f);
    unsigned r = u + 0x7FFFu + ((u >> 16) & 1u);   // round-to-nearest-even
    return (unsigned short)(r >> 16);
}

// ---------------- k0: weight prep (fully parallel; no serial tail block) ----------------
// blocks 0..191:   bf16 Wqkv·g1 rows (o = blk)
// blocks 192..447: bf16 wproj/wcls rows (r = blk-192)
// blocks 448..639: A[o],B[o] via block reduction (o = blk-448)
// blocks 640..660: woff^T transpose, one element per thread
__global__ __launch_bounds__(256) void k0_prep(
    const float* __restrict__ wqkv, const float* __restrict__ g1,
    const float* __restrict__ b1, const float* __restrict__ woff,
    const float* __restrict__ wproj, const float* __restrict__ wcls,
    float* __restrict__ ws)
{
    const int t = threadIdx.x;
    const int blk = blockIdx.x;
    if (blk < 192) {
        const int o = blk;
        unsigned short* wbf = (unsigned short*)(ws + OFF_WBF);
        wbf[o * 256 + t] = f2bf(wqkv[o * 256 + t] * g1[t]);
    } else if (blk < 448) {
        const int r = blk - 192;   // 0..255
        unsigned short* wpb = (unsigned short*)(ws + OFF_WPT);
        unsigned short* wcb = (unsigned short*)(ws + OFF_WCT);
        if (t < 64) wpb[r * 64 + t] = f2bf(wproj[r * 64 + t]);
        if (r < 80) wcb[r * 256 + t] = f2bf(wcls[r * 256 + t]);
    } else if (blk < 640) {
        const int o = blk - 448;   // 0..191
        __shared__ float sa[4], sb[4];
        float w = wqkv[o * 256 + t];
        float a = w * g1[t];
        float bb = w * b1[t];
        #pragma unroll
        for (int off = 1; off < 64; off <<= 1) {
            a  += __shfl_xor(a,  off, 64);
            bb += __shfl_xor(bb, off, 64);
        }
        const int wv = t >> 6;
        if ((t & 63) == 0) { sa[wv] = a; sb[wv] = bb; }
        __syncthreads();
        if (t == 0) {
            ws[OFF_AB + o]       = sa[0] + sa[1] + sa[2] + sa[3];
            ws[OFF_AB + 192 + o] = sb[0] + sb[1] + sb[2] + sb[3];
        }
    } else {
        int idx = (blk - 640) * 256 + t;   // enumerates (wo*32+ic)*18+o
        if (idx < 5184) {
            int o = idx % 18;
            int rest = idx / 18;           // wo*32 + ic
            int ic = rest & 31, wo = rest >> 5;
            ws[OFF_WFT + idx] = woff[(o * 32 + ic) * 9 + wo];
        }
    }
}

// ------ k1: QKV GEMM via bf16 MFMA, LN folded in epilogue, fp16 q/KV out ------
// grid 512 (b = blk&7 XCD-affine, row = blk>>3), block 512 = 8 waves.
__global__ __launch_bounds__(512) void k1_mfma(
    const float* __restrict__ x, float* __restrict__ ws)
{
    __shared__ float tile[64 * 193];   // 49.4 KB transpose tile [px][o] pad 193
    const int t = threadIdx.x;
    const int b = blockIdx.x & 7, row = blockIdx.x >> 3;
    const int wv = __builtin_amdgcn_readfirstlane(t >> 6);
    const int pt = wv & 3, oh = wv >> 2;
    const int lane = t & 63;
    const int quad = lane >> 4, pxl = lane & 15;
    const int colbase = row * 64 + pt * 16 + pxl;
    const unsigned short* wbf = (const unsigned short*)(ws + OFF_WBF);
    const float* AB = ws + OFF_AB;

    f32x4 acc[6];
    #pragma unroll
    for (int ot = 0; ot < 6; ++ot) acc[ot] = (f32x4){0.f, 0.f, 0.f, 0.f};
    float s = 0.f, ss = 0.f;
    const size_t xb0 = (size_t)b * DIM * HW + colbase;

    for (int ks = 0; ks < 8; ++ks) {
        const int cbase = ks * 32 + quad * 8;
        float xv[8];
        #pragma unroll
        for (int j = 0; j < 8; ++j) {
            xv[j] = x[xb0 + (size_t)(cbase + j) * HW];
            s += xv[j]; ss += xv[j] * xv[j];
        }
        union { bf16x8 v; unsigned short u[8]; } bfrag;
        #pragma unroll
        for (int j = 0; j < 8; ++j) bfrag.u[j] = f2bf(xv[j]);
        #pragma unroll
        for (int ot = 0; ot < 6; ++ot) {
            const int orow = (oh * 6 + ot) * 16 + pxl;
            union { float4 f; bf16x8 v; } afrag;
            afrag.f = *(const float4*)&wbf[orow * 256 + cbase];
            acc[ot] = __builtin_amdgcn_mfma_f32_16x16x32_bf16(afrag.v, bfrag.v, acc[ot], 0, 0, 0);
        }
    }

    s  += __shfl_xor(s, 16, 64);  s  += __shfl_xor(s, 32, 64);
    ss += __shfl_xor(ss, 16, 64); ss += __shfl_xor(ss, 32, 64);
    const float m = s * (1.f / 256.f);
    const float rsv = rsqrtf(ss * (1.f / 256.f) - m * m + 1e-5f);

    const int px = pt * 16 + pxl;
    #pragma unroll
    for (int ot = 0; ot < 6; ++ot) {
        #pragma unroll
        for (int r = 0; r < 4; ++r) {
            int o = (oh * 6 + ot) * 16 + quad * 4 + r;
            tile[px * 193 + o] = rsv * (acc[ot][r] - m * AB[o]) + AB[192 + o];
        }
    }
    __syncthreads();

    float*  qp  = ws + OFF_QP;
    __half* qth = (__half*)(ws + OFF_QT);
    __half* kvh = (__half*)(ws + OFF_KT);
    const int colrow = row * 64;
    #pragma unroll
    for (int it = 0; it < 8; ++it) {
        int idx = it * 512 + t;
        int o = idx >> 6, px2 = idx & 63;
        qp[(size_t)(b * 64 + o) * HW + colrow + px2] = tile[px2 * 193 + o];
    }
    #pragma unroll
    for (int it = 0; it < 8; ++it) {
        int idx = it * 512 + t;
        int px2 = idx >> 6, o = idx & 63;
        qth[(size_t)(b * HW + colrow + px2) * 64 + o] = __float2half(tile[px2 * 193 + o]);
    }
    #pragma unroll
    for (int it = 0; it < 4; ++it) {
        int idx = it * 512 + t;
        int px2 = idx >> 5, ch32 = idx & 31;
        int sB = ch32 >> 4, ch = ch32 & 15;
        kvh[(size_t)((2 * b) * HW + colrow + px2) * 64 + sB * 32 + ch]
            = __float2half(tile[px2 * 193 + 64 + ch32]);
    }
    #pragma unroll
    for (int it = 0; it < 4; ++it) {
        int idx = it * 512 + t;
        int px2 = idx >> 5, ch32 = idx & 31;
        int sB = ch32 >> 4, ch = ch32 & 15;
        kvh[(size_t)((2 * b + 1) * HW + colrow + px2) * 64 + sB * 32 + ch]
            = __float2half(tile[px2 * 193 + 96 + ch32]);
    }
    #pragma unroll
    for (int it = 0; it < 4; ++it) {
        int idx = it * 512 + t;
        int px2 = idx >> 5, ch32 = idx & 31;
        int sB = ch32 >> 4, ch = ch32 & 15;
        kvh[(size_t)((2 * b) * HW + colrow + px2) * 64 + sB * 32 + 16 + ch]
            = __float2half(tile[px2 * 193 + 128 + ch32]);
    }
    #pragma unroll
    for (int it = 0; it < 4; ++it) {
        int idx = it * 512 + t;
        int px2 = idx >> 5, ch32 = idx & 31;
        int sB = ch32 >> 4, ch = ch32 & 15;
        kvh[(size_t)((2 * b + 1) * HW + colrow + px2) * 64 + sB * 32 + 16 + ch]
            = __float2half(tile[px2 * 193 + 160 + ch32]);
    }
}

// ------- k2: depthwise 3x3 + LN(32) + GELU; q rows staged in LDS -------
// XCD-affine mapping: b = blk&7 (matches k1's qp[b] producer XCD), g=(blk>>3)&1,
// row = blk>>4. Per-XCD qp slice = 1 MB, t slice = 1 MB -> L2-resident.
__global__ __launch_bounds__(256) void k2_off_feat(
    const float* __restrict__ wdw, const float* __restrict__ g2, const float* __restrict__ b2,
    float* __restrict__ ws)
{
    __shared__ float qtile[3][32][64];              // 24 KB
    __shared__ float rsum[4][64], rsq[4][64], smv[64], srv[64];
    const int t = threadIdx.x;
    const int b = blockIdx.x & 7;
    const int rest = blockIdx.x >> 3;
    const int g = rest & 1;
    const int row = rest >> 1;
    const int bg = b * 2 + g;
    const int p = t & 63;
    const int cq = __builtin_amdgcn_readfirstlane(t >> 6);
    const float* qp = ws + OFF_QP;

    #pragma unroll
    for (int it = 0; it < 6; ++it) {
        int idx = it * 256 + t;
        int rc = idx >> 4;
        int seg = (idx & 15) << 2;
        int dyy = rc >> 5, ch = rc & 31;
        int y = row + dyy - 1;
        float4 v = make_float4(0.f, 0.f, 0.f, 0.f);
        if ((unsigned)y < 64u)
            v = *(const float4*)&qp[(size_t)(b * 64 + g * 32 + ch) * HW + y * 64 + seg];
        *(float4*)&qtile[dyy][ch][seg] = v;
    }
    __syncthreads();

    float vals[8];
    float s = 0.f, ss = 0.f;
    #pragma unroll
    for (int i = 0; i < 8; ++i) {
        int ch = cq * 8 + i;
        float a = 0.f;
        #pragma unroll
        for (int dy = 0; dy < 3; ++dy) {
            #pragma unroll
            for (int dx = 0; dx < 3; ++dx) {
                int xx = p + dx - 1;
                bool vld = (unsigned)xx < 64u;
                float q = qtile[dy][ch][vld ? xx : 0];
                a += (vld ? q : 0.f) * wdw[ch * 9 + dy * 3 + dx];
            }
        }
        vals[i] = a; s += a; ss += a * a;
    }
    rsum[cq][p] = s; rsq[cq][p] = ss;
    __syncthreads();
    if (t < 64) {
        float S = rsum[0][t] + rsum[1][t] + rsum[2][t] + rsum[3][t];
        float Q = rsq[0][t] + rsq[1][t] + rsq[2][t] + rsq[3][t];
        float m = S * (1.f / 32.f);
        float v = Q * (1.f / 32.f) - m * m;
        smv[t] = m; srv[t] = rsqrtf(v + 1e-5f);
    }
    __syncthreads();
    float m = smv[p], rv = srv[p];
    float* tb = ws + OFF_T;
    #pragma unroll
    for (int i = 0; i < 8; ++i) {
        int ch = cq * 8 + i;
        float u = (vals[i] - m) * rv * g2[ch] + b2[ch];
        float ge = 0.5f * u * (1.f + erff(u * 0.70710678118654752f));
        tb[(size_t)(bg * 32 + ch) * HW + row * 64 + p] = ge;
    }
}

// ------- k3: 3x3 conv 32->18 + tanh*5 + base offset, ic-split across waves -------
// Same XCD-affine mapping as k2: t[bg] and ob[bg] stay in the producing XCD's L2.
__global__ __launch_bounds__(256) void k3_pred_off(
    const float* __restrict__ boff, const float* __restrict__ off_in,
    float* __restrict__ ws)
{
    __shared__ float part[4 * 18 * 64];
    const int t = threadIdx.x;
    const int b = blockIdx.x & 7;
    const int rest = blockIdx.x >> 3;
    const int g = rest & 1;
    const int row = rest >> 1;
    const int bg = b * 2 + g;
    const int p = t & 63;
    const int icq = __builtin_amdgcn_readfirstlane(t >> 6);
    const float* tb = ws + OFF_T;
    const float* wfT = ws + OFF_WFT;
    float acc[18];
    #pragma unroll
    for (int o = 0; o < 18; ++o) acc[o] = 0.f;
    #pragma unroll
    for (int dy = 0; dy < 3; ++dy) {
        int y = row + dy - 1;
        if ((unsigned)y >= 64u) continue;
        #pragma unroll
        for (int dx = 0; dx < 3; ++dx) {
            int xx = p + dx - 1;
            bool vld = (unsigned)xx < 64u;
            int xc = vld ? xx : 0;
            int wo = dy * 3 + dx;
            #pragma unroll
            for (int i = 0; i < 8; ++i) {
                int ic = icq * 8 + i;
                float tv = tb[(size_t)(bg * 32 + ic) * HW + y * 64 + xc];
                tv = vld ? tv : 0.f;
                const float* wrow = wfT + (wo * 32 + ic) * 18;
                #pragma unroll
                for (int o = 0; o < 18; ++o)
                    acc[o] += tv * wrow[o];
            }
        }
    }
    #pragma unroll
    for (int o = 0; o < 18; ++o) part[(icq * 18 + o) * 64 + p] = acc[o];
    __syncthreads();
    float* ob = ws + OFF_OFFB;
    #pragma unroll
    for (int r = 0; r < 5; ++r) {
        int idx = t + r * 256;
        if (idx < 1152) {
            int o = idx >> 6, p2 = idx & 63;
            float v = part[o * 64 + p2] + part[(18 + o) * 64 + p2]
                    + part[(36 + o) * 64 + p2] + part[(54 + o) * 64 + p2] + boff[o];
            v = tanhf(v) * 5.0f + off_in[(size_t)(b * 18 + o) * HW + row * 64 + p2];
            ob[(size_t)(bg * 18 + o) * HW + row * 64 + p2] = v;
        }
    }
}

// ---- k4: deformable gather + softmax attn, fp16 KV; ao out = bf16 pix-major ----
// All 18 offset loads hoisted ahead of the tap loop so they pipeline once.
__global__ __launch_bounds__(256, 4) void k4_attn(
    const float* __restrict__ rpb, float* __restrict__ ws)
{
    __shared__ float rpb_l[NHD * NTAP * HC]; // 576 floats
    for (int i = threadIdx.x; i < NHD * NTAP * HC; i += 256) rpb_l[i] = rpb[i];
    __syncthreads();

    const int t = threadIdx.x;
    const int wave = __builtin_amdgcn_readfirstlane(t >> 6);
    const int g = wave & 1, pxh = wave >> 1;
    const int lane = t & 63;
    const int pxl = lane & 7;
    const int prt = lane >> 3;
    const int s    = prt >> 2;
    const int half = (prt >> 1) & 1;
    const int j    = prt & 1;
    const int b = blockIdx.x & 7;
    const int chunk = blockIdx.x >> 3;          // 0..255
    const int hw = chunk * 16 + pxh * 8 + pxl;
    const int pix = b * HW + hw;
    const int bg = b * 2 + g;
    const int head = g * 2 + s;

    const __half* qth = (const __half*)(ws + OFF_QT);
    const __half* kvh = (const __half*)(ws + OFF_KT);
    const float*  ob  = ws + OFF_OFFB;

    // hoist all 18 offset loads (independent; issue back-to-back)
    float rr_[NTAP], cc_[NTAP];
    #pragma unroll
    for (int n = 0; n < NTAP; ++n) {
        rr_[n] = ob[(size_t)(bg * 18 + 2 * n) * HW + hw];
        cc_[n] = ob[(size_t)(bg * 18 + 2 * n + 1) * HW + hw];
    }

    union F4H { float4 f; __half2 h[4]; };
    F4H qld;
    qld.f = *(const float4*)&qth[(size_t)pix * 64 + g * 32 + s * 16 + j * 8];
    const float qs = half ? 0.0f : 0.25f;
    float qv[8];
    #pragma unroll
    for (int i = 0; i < 4; ++i) {
        float2 q2 = __half22float2(qld.h[i]);
        qv[2 * i] = q2.x * qs; qv[2 * i + 1] = q2.y * qs;
    }

    const float4* rb4 = (const float4*)(rpb_l + head * (NTAP * HC) + j * 8);
    const __half* kvp = kvh + (size_t)(bg * HW) * 64 + prt * 8;

    __half2 av[NTAP][4];
    float logit[NTAP];

    #pragma unroll
    for (int n = 0; n < NTAP; ++n) {
        float r = rr_[n];
        float c = cc_[n];
        float y0f = floorf(r), x0f = floorf(c);
        float fy = r - y0f, fx = c - x0f;
        int iy0 = (int)y0f, ix0 = (int)x0f;
        float wts[4] = { (1.f - fx) * (1.f - fy), fx * (1.f - fy),
                         (1.f - fx) * fy,         fx * fy };
        __half2 acc0 = __float2half2_rn(0.f), acc1 = acc0, acc2 = acc0, acc3 = acc0;
        #pragma unroll
        for (int corner = 0; corner < 4; ++corner) {
            int cxx = ix0 + (corner & 1);
            int cyy = iy0 + (corner >> 1);
            bool vld = ((unsigned)cxx < 64u) && ((unsigned)cyy < 64u);
            float w = vld ? wts[corner] : 0.f;
            int cxc = min(max(cxx, 0), 63);
            int cyc = min(max(cyy, 0), 63);
            F4H kv;
            kv.f = *(const float4*)&kvp[(size_t)(cyc * 64 + cxc) * 64];
            __half2 w2 = __float2half2_rn(w);
            acc0 = __hfma2(kv.h[0], w2, acc0);
            acc1 = __hfma2(kv.h[1], w2, acc1);
            acc2 = __hfma2(kv.h[2], w2, acc2);
            acc3 = __hfma2(kv.h[3], w2, acc3);
        }
        av[n][0] = acc0; av[n][1] = acc1; av[n][2] = acc2; av[n][3] = acc3;
        float4 r0 = rb4[n * 4], r1 = rb4[n * 4 + 1];
        float2 a0 = __half22float2(acc0), a1 = __half22float2(acc1);
        float2 a2 = __half22float2(acc2), a3 = __half22float2(acc3);
        float part = qv[0] * (a0.x + r0.x) + qv[1] * (a0.y + r0.y)
                   + qv[2] * (a1.x + r0.z) + qv[3] * (a1.y + r0.w)
                   + qv[4] * (a2.x + r1.x) + qv[5] * (a2.y + r1.y)
                   + qv[6] * (a3.x + r1.z) + qv[7] * (a3.y + r1.w);
        part += __shfl_xor(part, 8, 64);
        part += __shfl_xor(part, 16, 64);
        logit[n] = part;
    }

    float m = logit[0];
    #pragma unroll
    for (int n = 1; n < NTAP; ++n) m = fmaxf(m, logit[n]);
    float l = 0.f;
    #pragma unroll
    for (int n = 0; n < NTAP; ++n) { logit[n] = __expf(logit[n] - m); l += logit[n]; }
    const float inv = 1.f / l;

    __half2 o0 = __float2half2_rn(0.f), o1 = o0, o2 = o0, o3 = o0;
    #pragma unroll
    for (int n = 0; n < NTAP; ++n) {
        __half2 p2 = __float2half2_rn(logit[n]);
        o0 = __hfma2(av[n][0], p2, o0);
        o1 = __hfma2(av[n][1], p2, o1);
        o2 = __hfma2(av[n][2], p2, o2);
        o3 = __hfma2(av[n][3], p2, o3);
    }
    if (half) {   // v-lanes write ao bf16 pixel-major [pix][64]
        unsigned short* aob = (unsigned short*)(ws + OFF_AOT);
        const int cb = head * 16 + j * 8;
        float2 f0 = __half22float2(o0), f1 = __half22float2(o1);
        float2 f2 = __half22float2(o2), f3 = __half22float2(o3);
        union { float4 f; unsigned short u[8]; } pk;
        pk.u[0] = f2bf(f0.x * inv); pk.u[1] = f2bf(f0.y * inv);
        pk.u[2] = f2bf(f1.x * inv); pk.u[3] = f2bf(f1.y * inv);
        pk.u[4] = f2bf(f2.x * inv); pk.u[5] = f2bf(f2.y * inv);
        pk.u[6] = f2bf(f3.x * inv); pk.u[7] = f2bf(f3.y * inv);
        *(float4*)&aob[(size_t)pix * 64 + cb] = pk.f;
    }
}

// ---- k5: fused proj(64->256)+bias+residual -> cls(256->80), all bf16 MFMA ----
__global__ __launch_bounds__(256) void k5_mfma(
    const float* __restrict__ x, const float* __restrict__ bproj,
    const float* __restrict__ bcls, float* __restrict__ ws, float* __restrict__ out)
{
    __shared__ unsigned short tmp[64][264];   // bf16 [px][256 c] pad 8 -> 33.8 KB
    const int t = threadIdx.x;
    const int b = blockIdx.x & 7, row = blockIdx.x >> 3;
    const int wv = __builtin_amdgcn_readfirstlane(t >> 6);
    const int lane = t & 63, quad = lane >> 4, pxl = lane & 15;
    const int px = wv * 16 + pxl;
    const int pixcol = row * 64 + px;
    const size_t pix = (size_t)b * HW + pixcol;
    const unsigned short* aob = (const unsigned short*)(ws + OFF_AOT);
    const unsigned short* wpb = (const unsigned short*)(ws + OFF_WPT);
    const unsigned short* wcb = (const unsigned short*)(ws + OFF_WCT);

    union FB { float4 f; bf16x8 v; };
    FB bf0, bf1;
    bf0.f = *(const float4*)&aob[pix * 64 + quad * 8];
    bf1.f = *(const float4*)&aob[pix * 64 + 32 + quad * 8];

    // proj: 16 o-tiles of 16; k = 64 (2 MFMA)
    #pragma unroll 4
    for (int ot = 0; ot < 16; ++ot) {
        f32x4 acc = (f32x4){0.f, 0.f, 0.f, 0.f};
        FB a0, a1;
        const int om = ot * 16 + pxl;
        a0.f = *(const float4*)&wpb[om * 64 + quad * 8];
        a1.f = *(const float4*)&wpb[om * 64 + 32 + quad * 8];
        acc = __builtin_amdgcn_mfma_f32_16x16x32_bf16(a0.v, bf0.v, acc, 0, 0, 0);
        acc = __builtin_amdgcn_mfma_f32_16x16x32_bf16(a1.v, bf1.v, acc, 0, 0, 0);
        union { unsigned short u[4]; ushort2 s2[2]; } pk;
        #pragma unroll
        for (int r = 0; r < 4; ++r) {
            int o = ot * 16 + quad * 4 + r;
            float v = acc[r] + bproj[o] + x[(size_t)(b * DIM + o) * HW + pixcol];
            pk.u[r] = f2bf(v);
        }
        *(ushort4*)&tmp[px][ot * 16 + quad * 4] = *(ushort4*)pk.u;
    }
    __syncthreads();

    // cls: 5 oc-tiles of 16; k = 256 (8 chunks)
    f32x4 acc2[5];
    #pragma unroll
    for (int oc = 0; oc < 5; ++oc) acc2[oc] = (f32x4){0.f, 0.f, 0.f, 0.f};
    #pragma unroll
    for (int kc = 0; kc < 8; ++kc) {
        FB bb;
        bb.f = *(const float4*)&tmp[px][kc * 32 + quad * 8];
        #pragma unroll
        for (int oc = 0; oc < 5; ++oc) {
            FB aa;
            aa.f = *(const float4*)&wcb[(oc * 16 + pxl) * 256 + kc * 32 + quad * 8];
            acc2[oc] = __builtin_amdgcn_mfma_f32_16x16x32_bf16(aa.v, bb.v, acc2[oc], 0, 0, 0);
        }
    }
    #pragma unroll
    for (int oc = 0; oc < 5; ++oc) {
        #pragma unroll
        for (int r = 0; r < 4; ++r) {
            int o = oc * 16 + quad * 4 + r;
            out[(size_t)(b * NCLS + o) * HW + pixcol] = acc2[oc][r] + bcls[o];
        }
    }
}

extern "C" void kernel_launch(void* const* d_in, const int* in_sizes, int n_in,
                              void* d_out, int out_size, void* d_ws, size_t ws_size,
                              hipStream_t stream)
{
    const float* x     = (const float*)d_in[0];
    const float* off   = (const float*)d_in[1];
    const float* g1    = (const float*)d_in[2];
    const float* b1    = (const float*)d_in[3];
    const float* wqkv  = (const float*)d_in[4];
    const float* wdw   = (const float*)d_in[5];
    const float* g2    = (const float*)d_in[6];
    const float* b2    = (const float*)d_in[7];
    const float* woff  = (const float*)d_in[8];
    const float* boff  = (const float*)d_in[9];
    const float* rpb   = (const float*)d_in[10];
    const float* wproj = (const float*)d_in[11];
    const float* bproj = (const float*)d_in[12];
    const float* wcls  = (const float*)d_in[13];
    const float* bcls  = (const float*)d_in[14];
    float* ws  = (float*)d_ws;
    float* out = (float*)d_out;

    hipLaunchKernelGGL(k0_prep,     dim3(661),  dim3(256), 0, stream, wqkv, g1, b1, woff, wproj, wcls, ws);
    hipLaunchKernelGGL(k1_mfma,     dim3(512),  dim3(512), 0, stream, x, ws);
    hipLaunchKernelGGL(k2_off_feat, dim3(1024), dim3(256), 0, stream, wdw, g2, b2, ws);
    hipLaunchKernelGGL(k3_pred_off, dim3(1024), dim3(256), 0, stream, boff, off, ws);
    hipLaunchKernelGGL(k4_attn,     dim3(2048), dim3(256), 0, stream, rpb, ws);
    hipLaunchKernelGGL(k5_mfma,     dim3(512),  dim3(256), 0, stream, x, bproj, bcls, ws, out);
}

// Round 4
// 218.696 us; speedup vs baseline: 1.1898x; 1.0577x over previous
//
#include <hip/hip_runtime.h>
#include <hip/hip_fp16.h>
#include <math.h>

// Problem constants
#define BB   8
#define HW   4096
#define BHW  32768
#define DIM  256
#define CR   64
#define GC   32
#define NHD  4
#define HC   16
#define NTAP 9
#define NCLS 80

// workspace layout (float offsets)
#define OFF_QP   0u          // q planar   [B][64][H][W] fp32       2,097,152
#define OFF_QT   2097152u    // q pix-major[B*HW][64] fp16          1,048,576 (floats of space)
#define OFF_KT   4194304u    // KV fp16 [BG][HW][2 sub][k16|v16]    2,097,152 (floats of space)
// --- OFF_T span (8,388,608..10,485,760) hosts: WBF/AB (k0->k1), T16 (k2->k3) ---
#define OFF_WBF  8388608u    // W_qkv·g1 bf16 [192][256]            24,576 float-slots
#define OFF_AB   8437760u    // A[192], B[192]                      384
#define OFF_T16  8650752u    // t fp16 pix-major [BG][HW][32]       1,048,576 float-slots
// ------------------------------------------------------------------------
#define OFF_OFFB 10485760u   // off planar [BG][18][H][W]           1,179,648
#define OFF_AOT  11665408u   // attn out bf16 [B*HW][64] pix-major  1,048,576 float-slots used
#define OFF_WPT  13762560u   // wproj bf16 [256][64]                8,192 float-slots used
#define OFF_WCT  13778944u   // wcls  bf16 [80][256]                10,240 float-slots used
#define OFF_WFT  13799424u   // woff MFMA A-frags fp16 [2][9][64][8] 4,608 float-slots used

typedef short    bf16x8 __attribute__((ext_vector_type(8)));
typedef _Float16 f16x8  __attribute__((ext_vector_type(8)));
typedef float    f32x4  __attribute__((ext_vector_type(4)));

__device__ __forceinline__ unsigned short f2bf(float f) {
    unsigned u = __float_as_uint(f);
    unsigned r = u + 0x7FFFu + ((u >> 16) & 1u);   // round-to-nearest-even
    return (unsigned short)(r >> 16);
}

// ---------------- k0: weight prep (fully parallel) ----------------
// blocks 0..191:   bf16 Wqkv·g1 rows (o = blk)
// blocks 192..447: bf16 wproj/wcls rows (r = blk-192)
// blocks 448..639: A[o],B[o] via block reduction (o = blk-448)
// blocks 640..675: woff -> fp16 MFMA A-fragments [m][wo][lane][8]
__global__ __launch_bounds__(256) void k0_prep(
    const float* __restrict__ wqkv, const float* __restrict__ g1,
    const float* __restrict__ b1, const float* __restrict__ woff,
    const float* __restrict__ wproj, const float* __restrict__ wcls,
    float* __restrict__ ws)
{
    const int t = threadIdx.x;
    const int blk = blockIdx.x;
    if (blk < 192) {
        const int o = blk;
        unsigned short* wbf = (unsigned short*)(ws + OFF_WBF);
        wbf[o * 256 + t] = f2bf(wqkv[o * 256 + t] * g1[t]);
    } else if (blk < 448) {
        const int r = blk - 192;   // 0..255
        unsigned short* wpb = (unsigned short*)(ws + OFF_WPT);
        unsigned short* wcb = (unsigned short*)(ws + OFF_WCT);
        if (t < 64) wpb[r * 64 + t] = f2bf(wproj[r * 64 + t]);
        if (r < 80) wcb[r * 256 + t] = f2bf(wcls[r * 256 + t]);
    } else if (blk < 640) {
        const int o = blk - 448;   // 0..191
        __shared__ float sa[4], sb[4];
        float w = wqkv[o * 256 + t];
        float a = w * g1[t];
        float bb = w * b1[t];
        #pragma unroll
        for (int off = 1; off < 64; off <<= 1) {
            a  += __shfl_xor(a,  off, 64);
            bb += __shfl_xor(bb, off, 64);
        }
        const int wv = t >> 6;
        if ((t & 63) == 0) { sa[wv] = a; sb[wv] = bb; }
        __syncthreads();
        if (t == 0) {
            ws[OFF_AB + o]       = sa[0] + sa[1] + sa[2] + sa[3];
            ws[OFF_AB + 192 + o] = sb[0] + sb[1] + sb[2] + sb[3];
        }
    } else {
        // wfA[m][wo][lane][j]: value = W[o = m*16 + (lane&15)][ic = (lane>>4)*8 + j] at tap wo
        int idx = (blk - 640) * 256 + t;   // 0..9215
        if (idx < 2 * 9 * 64 * 8) {
            int j = idx & 7;
            int lane = (idx >> 3) & 63;
            int mw = idx >> 9;             // 0..17
            int m = mw / 9, wo = mw % 9;
            int o = m * 16 + (lane & 15);
            int ic = (lane >> 4) * 8 + j;
            float v = (o < 18) ? woff[(o * 32 + ic) * 9 + wo] : 0.f;
            ((__half*)(ws + OFF_WFT))[idx] = __float2half(v);
        }
    }
}

// ------ k1: QKV GEMM via bf16 MFMA, LN folded in epilogue, fp16 q/KV out ------
// grid 512 (b = blk&7 XCD-affine, row = blk>>3), block 512 = 8 waves.
__global__ __launch_bounds__(512) void k1_mfma(
    const float* __restrict__ x, float* __restrict__ ws)
{
    __shared__ float tile[64 * 193];   // 49.4 KB transpose tile [px][o] pad 193
    const int t = threadIdx.x;
    const int b = blockIdx.x & 7, row = blockIdx.x >> 3;
    const int wv = __builtin_amdgcn_readfirstlane(t >> 6);
    const int pt = wv & 3, oh = wv >> 2;
    const int lane = t & 63;
    const int quad = lane >> 4, pxl = lane & 15;
    const int colbase = row * 64 + pt * 16 + pxl;
    const unsigned short* wbf = (const unsigned short*)(ws + OFF_WBF);
    const float* AB = ws + OFF_AB;

    f32x4 acc[6];
    #pragma unroll
    for (int ot = 0; ot < 6; ++ot) acc[ot] = (f32x4){0.f, 0.f, 0.f, 0.f};
    float s = 0.f, ss = 0.f;
    const size_t xb0 = (size_t)b * DIM * HW + colbase;

    for (int ks = 0; ks < 8; ++ks) {
        const int cbase = ks * 32 + quad * 8;
        float xv[8];
        #pragma unroll
        for (int j = 0; j < 8; ++j) {
            xv[j] = x[xb0 + (size_t)(cbase + j) * HW];
            s += xv[j]; ss += xv[j] * xv[j];
        }
        union { bf16x8 v; unsigned short u[8]; } bfrag;
        #pragma unroll
        for (int j = 0; j < 8; ++j) bfrag.u[j] = f2bf(xv[j]);
        #pragma unroll
        for (int ot = 0; ot < 6; ++ot) {
            const int orow = (oh * 6 + ot) * 16 + pxl;
            union { float4 f; bf16x8 v; } afrag;
            afrag.f = *(const float4*)&wbf[orow * 256 + cbase];
            acc[ot] = __builtin_amdgcn_mfma_f32_16x16x32_bf16(afrag.v, bfrag.v, acc[ot], 0, 0, 0);
        }
    }

    s  += __shfl_xor(s, 16, 64);  s  += __shfl_xor(s, 32, 64);
    ss += __shfl_xor(ss, 16, 64); ss += __shfl_xor(ss, 32, 64);
    const float m = s * (1.f / 256.f);
    const float rsv = rsqrtf(ss * (1.f / 256.f) - m * m + 1e-5f);

    const int px = pt * 16 + pxl;
    #pragma unroll
    for (int ot = 0; ot < 6; ++ot) {
        #pragma unroll
        for (int r = 0; r < 4; ++r) {
            int o = (oh * 6 + ot) * 16 + quad * 4 + r;
            tile[px * 193 + o] = rsv * (acc[ot][r] - m * AB[o]) + AB[192 + o];
        }
    }
    __syncthreads();

    float*  qp  = ws + OFF_QP;
    __half* qth = (__half*)(ws + OFF_QT);
    __half* kvh = (__half*)(ws + OFF_KT);
    const int colrow = row * 64;
    #pragma unroll
    for (int it = 0; it < 8; ++it) {
        int idx = it * 512 + t;
        int o = idx >> 6, px2 = idx & 63;
        qp[(size_t)(b * 64 + o) * HW + colrow + px2] = tile[px2 * 193 + o];
    }
    #pragma unroll
    for (int it = 0; it < 8; ++it) {
        int idx = it * 512 + t;
        int px2 = idx >> 6, o = idx & 63;
        qth[(size_t)(b * HW + colrow + px2) * 64 + o] = __float2half(tile[px2 * 193 + o]);
    }
    #pragma unroll
    for (int it = 0; it < 4; ++it) {
        int idx = it * 512 + t;
        int px2 = idx >> 5, ch32 = idx & 31;
        int sB = ch32 >> 4, ch = ch32 & 15;
        kvh[(size_t)((2 * b) * HW + colrow + px2) * 64 + sB * 32 + ch]
            = __float2half(tile[px2 * 193 + 64 + ch32]);
    }
    #pragma unroll
    for (int it = 0; it < 4; ++it) {
        int idx = it * 512 + t;
        int px2 = idx >> 5, ch32 = idx & 31;
        int sB = ch32 >> 4, ch = ch32 & 15;
        kvh[(size_t)((2 * b + 1) * HW + colrow + px2) * 64 + sB * 32 + ch]
            = __float2half(tile[px2 * 193 + 96 + ch32]);
    }
    #pragma unroll
    for (int it = 0; it < 4; ++it) {
        int idx = it * 512 + t;
        int px2 = idx >> 5, ch32 = idx & 31;
        int sB = ch32 >> 4, ch = ch32 & 15;
        kvh[(size_t)((2 * b) * HW + colrow + px2) * 64 + sB * 32 + 16 + ch]
            = __float2half(tile[px2 * 193 + 128 + ch32]);
    }
    #pragma unroll
    for (int it = 0; it < 4; ++it) {
        int idx = it * 512 + t;
        int px2 = idx >> 5, ch32 = idx & 31;
        int sB = ch32 >> 4, ch = ch32 & 15;
        kvh[(size_t)((2 * b + 1) * HW + colrow + px2) * 64 + sB * 32 + 16 + ch]
            = __float2half(tile[px2 * 193 + 160 + ch32]);
    }
}

// ------- k2: depthwise 3x3 + LN(32) + GELU; writes t fp16 pix-major [bg][pix][32] -------
// XCD-affine mapping: b = blk&7 (matches k1's qp[b] producer XCD), g=(blk>>3)&1, row=blk>>4.
__global__ __launch_bounds__(256) void k2_off_feat(
    const float* __restrict__ wdw, const float* __restrict__ g2, const float* __restrict__ b2,
    float* __restrict__ ws)
{
    __shared__ float qtile[3][32][64];              // 24 KB
    __shared__ float rsum[4][64], rsq[4][64], smv[64], srv[64];
    const int t = threadIdx.x;
    const int b = blockIdx.x & 7;
    const int rest = blockIdx.x >> 3;
    const int g = rest & 1;
    const int row = rest >> 1;
    const int bg = b * 2 + g;
    const int p = t & 63;
    const int cq = __builtin_amdgcn_readfirstlane(t >> 6);
    const float* qp = ws + OFF_QP;

    #pragma unroll
    for (int it = 0; it < 6; ++it) {
        int idx = it * 256 + t;
        int rc = idx >> 4;
        int seg = (idx & 15) << 2;
        int dyy = rc >> 5, ch = rc & 31;
        int y = row + dyy - 1;
        float4 v = make_float4(0.f, 0.f, 0.f, 0.f);
        if ((unsigned)y < 64u)
            v = *(const float4*)&qp[(size_t)(b * 64 + g * 32 + ch) * HW + y * 64 + seg];
        *(float4*)&qtile[dyy][ch][seg] = v;
    }
    __syncthreads();

    float vals[8];
    float s = 0.f, ss = 0.f;
    #pragma unroll
    for (int i = 0; i < 8; ++i) {
        int ch = cq * 8 + i;
        float a = 0.f;
        #pragma unroll
        for (int dy = 0; dy < 3; ++dy) {
            #pragma unroll
            for (int dx = 0; dx < 3; ++dx) {
                int xx = p + dx - 1;
                bool vld = (unsigned)xx < 64u;
                float q = qtile[dy][ch][vld ? xx : 0];
                a += (vld ? q : 0.f) * wdw[ch * 9 + dy * 3 + dx];
            }
        }
        vals[i] = a; s += a; ss += a * a;
    }
    rsum[cq][p] = s; rsq[cq][p] = ss;
    __syncthreads();
    if (t < 64) {
        float S = rsum[0][t] + rsum[1][t] + rsum[2][t] + rsum[3][t];
        float Q = rsq[0][t] + rsq[1][t] + rsq[2][t] + rsq[3][t];
        float m = S * (1.f / 32.f);
        float v = Q * (1.f / 32.f) - m * m;
        smv[t] = m; srv[t] = rsqrtf(v + 1e-5f);
    }
    __syncthreads();
    float m = smv[p], rv = srv[p];
    __half* tb16 = (__half*)(ws + OFF_T16);
    #pragma unroll
    for (int i = 0; i < 8; ++i) {
        int ch = cq * 8 + i;
        float u = (vals[i] - m) * rv * g2[ch] + b2[ch];
        vals[i] = 0.5f * u * (1.f + erff(u * 0.70710678118654752f));
    }
    union { float4 f; __half2 h[4]; } o16;
    #pragma unroll
    for (int i = 0; i < 4; ++i) o16.h[i] = __floats2half2_rn(vals[2 * i], vals[2 * i + 1]);
    *(float4*)&tb16[((size_t)bg * HW + row * 64 + p) * 32 + cq * 8] = o16.f;
}

// ------- k3: 3x3 conv 32->18 as implicit-GEMM fp16 MFMA + tanh*5 + base offset -------
// grid 512: b=blk&7 (XCD-affine), g, rowgrp(4 rows, one per wave), xhalf(32 px).
// Per wave: 9 K-chunks (taps) x 2 px-tiles x 2 M-tiles = 36 mfma_f32_16x16x32_f16.
__global__ __launch_bounds__(256) void k3_mfma(
    const float* __restrict__ boff, const float* __restrict__ off_in,
    float* __restrict__ ws)
{
    const int t = threadIdx.x;
    const int b = blockIdx.x & 7;
    const int rest = blockIdx.x >> 3;     // 6 bits: g | rowgrp(4) | xh
    const int g = rest & 1;
    const int rowgrp = (rest >> 1) & 15;
    const int xh = rest >> 5;
    const int wv = __builtin_amdgcn_readfirstlane(t >> 6);
    const int lane = t & 63;
    const int quad = lane >> 4, pxl = lane & 15;
    const int row = rowgrp * 4 + wv;
    const int bg = b * 2 + g;
    const __half* t16 = (const __half*)(ws + OFF_T16);
    const __half* wfA = (const __half*)(ws + OFF_WFT);

    f32x4 acc[2][2];   // [px-tile][m-tile]
    #pragma unroll
    for (int i = 0; i < 2; ++i)
        #pragma unroll
        for (int j = 0; j < 2; ++j) acc[i][j] = (f32x4){0.f, 0.f, 0.f, 0.f};

    union FH { float4 f; f16x8 h; };
    #pragma unroll
    for (int wo = 0; wo < 9; ++wo) {
        const int dy = wo / 3, dx = wo % 3;
        const int y = row + dy - 1;
        const bool yv = (unsigned)y < 64u;
        FH a0, a1;
        a0.f = *(const float4*)&wfA[(size_t)((0 * 9 + wo) * 64 + lane) * 8];
        a1.f = *(const float4*)&wfA[(size_t)((1 * 9 + wo) * 64 + lane) * 8];
        #pragma unroll
        for (int tile = 0; tile < 2; ++tile) {
            const int x = xh * 32 + tile * 16 + pxl + dx - 1;
            FH bf;
            bf.f = make_float4(0.f, 0.f, 0.f, 0.f);
            if (yv && (unsigned)x < 64u)
                bf.f = *(const float4*)&t16[((size_t)bg * HW + y * 64 + x) * 32 + quad * 8];
            acc[tile][0] = __builtin_amdgcn_mfma_f32_16x16x32_f16(a0.h, bf.h, acc[tile][0], 0, 0, 0);
            acc[tile][1] = __builtin_amdgcn_mfma_f32_16x16x32_f16(a1.h, bf.h, acc[tile][1], 0, 0, 0);
        }
    }

    float* ob = ws + OFF_OFFB;
    #pragma unroll
    for (int tile = 0; tile < 2; ++tile) {
        const int px = xh * 32 + tile * 16 + pxl;
        #pragma unroll
        for (int mi = 0; mi < 2; ++mi) {
            #pragma unroll
            for (int r = 0; r < 4; ++r) {
                int o = mi * 16 + quad * 4 + r;
                if (o < 18) {
                    float v = acc[tile][mi][r] + boff[o];
                    v = tanhf(v) * 5.0f + off_in[(size_t)(b * 18 + o) * HW + row * 64 + px];
                    ob[(size_t)(bg * 18 + o) * HW + row * 64 + px] = v;
                }
            }
        }
    }
}

// ---- k4: deformable gather + softmax attn, fp16 KV; ao out = bf16 pix-major ----
// All 18 offset loads hoisted ahead of the tap loop so they pipeline once.
__global__ __launch_bounds__(256, 4) void k4_attn(
    const float* __restrict__ rpb, float* __restrict__ ws)
{
    __shared__ float rpb_l[NHD * NTAP * HC]; // 576 floats
    for (int i = threadIdx.x; i < NHD * NTAP * HC; i += 256) rpb_l[i] = rpb[i];
    __syncthreads();

    const int t = threadIdx.x;
    const int wave = __builtin_amdgcn_readfirstlane(t >> 6);
    const int g = wave & 1, pxh = wave >> 1;
    const int lane = t & 63;
    const int pxl = lane & 7;
    const int prt = lane >> 3;
    const int s    = prt >> 2;
    const int half = (prt >> 1) & 1;
    const int j    = prt & 1;
    const int b = blockIdx.x & 7;
    const int chunk = blockIdx.x >> 3;          // 0..255
    const int hw = chunk * 16 + pxh * 8 + pxl;
    const int pix = b * HW + hw;
    const int bg = b * 2 + g;
    const int head = g * 2 + s;

    const __half* qth = (const __half*)(ws + OFF_QT);
    const __half* kvh = (const __half*)(ws + OFF_KT);
    const float*  ob  = ws + OFF_OFFB;

    // hoist all 18 offset loads (independent; issue back-to-back)
    float rr_[NTAP], cc_[NTAP];
    #pragma unroll
    for (int n = 0; n < NTAP; ++n) {
        rr_[n] = ob[(size_t)(bg * 18 + 2 * n) * HW + hw];
        cc_[n] = ob[(size_t)(bg * 18 + 2 * n + 1) * HW + hw];
    }

    union F4H { float4 f; __half2 h[4]; };
    F4H qld;
    qld.f = *(const float4*)&qth[(size_t)pix * 64 + g * 32 + s * 16 + j * 8];
    const float qs = half ? 0.0f : 0.25f;
    float qv[8];
    #pragma unroll
    for (int i = 0; i < 4; ++i) {
        float2 q2 = __half22float2(qld.h[i]);
        qv[2 * i] = q2.x * qs; qv[2 * i + 1] = q2.y * qs;
    }

    const float4* rb4 = (const float4*)(rpb_l + head * (NTAP * HC) + j * 8);
    const __half* kvp = kvh + (size_t)(bg * HW) * 64 + prt * 8;

    __half2 av[NTAP][4];
    float logit[NTAP];

    #pragma unroll
    for (int n = 0; n < NTAP; ++n) {
        float r = rr_[n];
        float c = cc_[n];
        float y0f = floorf(r), x0f = floorf(c);
        float fy = r - y0f, fx = c - x0f;
        int iy0 = (int)y0f, ix0 = (int)x0f;
        float wts[4] = { (1.f - fx) * (1.f - fy), fx * (1.f - fy),
                         (1.f - fx) * fy,         fx * fy };
        __half2 acc0 = __float2half2_rn(0.f), acc1 = acc0, acc2 = acc0, acc3 = acc0;
        #pragma unroll
        for (int corner = 0; corner < 4; ++corner) {
            int cxx = ix0 + (corner & 1);
            int cyy = iy0 + (corner >> 1);
            bool vld = ((unsigned)cxx < 64u) && ((unsigned)cyy < 64u);
            float w = vld ? wts[corner] : 0.f;
            int cxc = min(max(cxx, 0), 63);
            int cyc = min(max(cyy, 0), 63);
            F4H kv;
            kv.f = *(const float4*)&kvp[(size_t)(cyc * 64 + cxc) * 64];
            __half2 w2 = __float2half2_rn(w);
            acc0 = __hfma2(kv.h[0], w2, acc0);
            acc1 = __hfma2(kv.h[1], w2, acc1);
            acc2 = __hfma2(kv.h[2], w2, acc2);
            acc3 = __hfma2(kv.h[3], w2, acc3);
        }
        av[n][0] = acc0; av[n][1] = acc1; av[n][2] = acc2; av[n][3] = acc3;
        float4 r0 = rb4[n * 4], r1 = rb4[n * 4 + 1];
        float2 a0 = __half22float2(acc0), a1 = __half22float2(acc1);
        float2 a2 = __half22float2(acc2), a3 = __half22float2(acc3);
        float part = qv[0] * (a0.x + r0.x) + qv[1] * (a0.y + r0.y)
                   + qv[2] * (a1.x + r0.z) + qv[3] * (a1.y + r0.w)
                   + qv[4] * (a2.x + r1.x) + qv[5] * (a2.y + r1.y)
                   + qv[6] * (a3.x + r1.z) + qv[7] * (a3.y + r1.w);
        part += __shfl_xor(part, 8, 64);
        part += __shfl_xor(part, 16, 64);
        logit[n] = part;
    }

    float m = logit[0];
    #pragma unroll
    for (int n = 1; n < NTAP; ++n) m = fmaxf(m, logit[n]);
    float l = 0.f;
    #pragma unroll
    for (int n = 0; n < NTAP; ++n) { logit[n] = __expf(logit[n] - m); l += logit[n]; }
    const float inv = 1.f / l;

    __half2 o0 = __float2half2_rn(0.f), o1 = o0, o2 = o0, o3 = o0;
    #pragma unroll
    for (int n = 0; n < NTAP; ++n) {
        __half2 p2 = __float2half2_rn(logit[n]);
        o0 = __hfma2(av[n][0], p2, o0);
        o1 = __hfma2(av[n][1], p2, o1);
        o2 = __hfma2(av[n][2], p2, o2);
        o3 = __hfma2(av[n][3], p2, o3);
    }
    if (half) {   // v-lanes write ao bf16 pixel-major [pix][64]
        unsigned short* aob = (unsigned short*)(ws + OFF_AOT);
        const int cb = head * 16 + j * 8;
        float2 f0 = __half22float2(o0), f1 = __half22float2(o1);
        float2 f2 = __half22float2(o2), f3 = __half22float2(o3);
        union { float4 f; unsigned short u[8]; } pk;
        pk.u[0] = f2bf(f0.x * inv); pk.u[1] = f2bf(f0.y * inv);
        pk.u[2] = f2bf(f1.x * inv); pk.u[3] = f2bf(f1.y * inv);
        pk.u[4] = f2bf(f2.x * inv); pk.u[5] = f2bf(f2.y * inv);
        pk.u[6] = f2bf(f3.x * inv); pk.u[7] = f2bf(f3.y * inv);
        *(float4*)&aob[(size_t)pix * 64 + cb] = pk.f;
    }
}

// ---- k5: fused proj(64->256)+bias+residual -> cls(256->80), all bf16 MFMA ----
__global__ __launch_bounds__(256) void k5_mfma(
    const float* __restrict__ x, const float* __restrict__ bproj,
    const float* __restrict__ bcls, float* __restrict__ ws, float* __restrict__ out)
{
    __shared__ unsigned short tmp[64][264];   // bf16 [px][256 c] pad 8 -> 33.8 KB
    const int t = threadIdx.x;
    const int b = blockIdx.x & 7, row = blockIdx.x >> 3;
    const int wv = __builtin_amdgcn_readfirstlane(t >> 6);
    const int lane = t & 63, quad = lane >> 4, pxl = lane & 15;
    const int px = wv * 16 + pxl;
    const int pixcol = row * 64 + px;
    const size_t pix = (size_t)b * HW + pixcol;
    const unsigned short* aob = (const unsigned short*)(ws + OFF_AOT);
    const unsigned short* wpb = (const unsigned short*)(ws + OFF_WPT);
    const unsigned short* wcb = (const unsigned short*)(ws + OFF_WCT);

    union FB { float4 f; bf16x8 v; };
    FB bf0, bf1;
    bf0.f = *(const float4*)&aob[pix * 64 + quad * 8];
    bf1.f = *(const float4*)&aob[pix * 64 + 32 + quad * 8];

    // proj: 16 o-tiles of 16; k = 64 (2 MFMA)
    #pragma unroll 4
    for (int ot = 0; ot < 16; ++ot) {
        f32x4 acc = (f32x4){0.f, 0.f, 0.f, 0.f};
        FB a0, a1;
        const int om = ot * 16 + pxl;
        a0.f = *(const float4*)&wpb[om * 64 + quad * 8];
        a1.f = *(const float4*)&wpb[om * 64 + 32 + quad * 8];
        acc = __builtin_amdgcn_mfma_f32_16x16x32_bf16(a0.v, bf0.v, acc, 0, 0, 0);
        acc = __builtin_amdgcn_mfma_f32_16x16x32_bf16(a1.v, bf1.v, acc, 0, 0, 0);
        union { unsigned short u[4]; ushort2 s2[2]; } pk;
        #pragma unroll
        for (int r = 0; r < 4; ++r) {
            int o = ot * 16 + quad * 4 + r;
            float v = acc[r] + bproj[o] + x[(size_t)(b * DIM + o) * HW + pixcol];
            pk.u[r] = f2bf(v);
        }
        *(ushort4*)&tmp[px][ot * 16 + quad * 4] = *(ushort4*)pk.u;
    }
    __syncthreads();

    // cls: 5 oc-tiles of 16; k = 256 (8 chunks)
    f32x4 acc2[5];
    #pragma unroll
    for (int oc = 0; oc < 5; ++oc) acc2[oc] = (f32x4){0.f, 0.f, 0.f, 0.f};
    #pragma unroll
    for (int kc = 0; kc < 8; ++kc) {
        FB bb;
        bb.f = *(const float4*)&tmp[px][kc * 32 + quad * 8];
        #pragma unroll
        for (int oc = 0; oc < 5; ++oc) {
            FB aa;
            aa.f = *(const float4*)&wcb[(oc * 16 + pxl) * 256 + kc * 32 + quad * 8];
            acc2[oc] = __builtin_amdgcn_mfma_f32_16x16x32_bf16(aa.v, bb.v, acc2[oc], 0, 0, 0);
        }
    }
    #pragma unroll
    for (int oc = 0; oc < 5; ++oc) {
        #pragma unroll
        for (int r = 0; r < 4; ++r) {
            int o = oc * 16 + quad * 4 + r;
            out[(size_t)(b * NCLS + o) * HW + pixcol] = acc2[oc][r] + bcls[o];
        }
    }
}

extern "C" void kernel_launch(void* const* d_in, const int* in_sizes, int n_in,
                              void* d_out, int out_size, void* d_ws, size_t ws_size,
                              hipStream_t stream)
{
    const float* x     = (const float*)d_in[0];
    const float* off   = (const float*)d_in[1];
    const float* g1    = (const float*)d_in[2];
    const float* b1    = (const float*)d_in[3];
    const float* wqkv  = (const float*)d_in[4];
    const float* wdw   = (const float*)d_in[5];
    const float* g2    = (const float*)d_in[6];
    const float* b2    = (const float*)d_in[7];
    const float* woff  = (const float*)d_in[8];
    const float* boff  = (const float*)d_in[9];
    const float* rpb   = (const float*)d_in[10];
    const float* wproj = (const float*)d_in[11];
    const float* bproj = (const float*)d_in[12];
    const float* wcls  = (const float*)d_in[13];
    const float* bcls  = (const float*)d_in[14];
    float* ws  = (float*)d_ws;
    float* out = (float*)d_out;

    hipLaunchKernelGGL(k0_prep,     dim3(676),  dim3(256), 0, stream, wqkv, g1, b1, woff, wproj, wcls, ws);
    hipLaunchKernelGGL(k1_mfma,     dim3(512),  dim3(512), 0, stream, x, ws);
    hipLaunchKernelGGL(k2_off_feat, dim3(1024), dim3(256), 0, stream, wdw, g2, b2, ws);
    hipLaunchKernelGGL(k3_mfma,     dim3(512),  dim3(256), 0, stream, boff, off, ws);
    hipLaunchKernelGGL(k4_attn,     dim3(2048), dim3(256), 0, stream, rpb, ws);
    hipLaunchKernelGGL(k5_mfma,     dim3(512),  dim3(256), 0, stream, x, bproj, bcls, ws, out);
}

// Round 5
// 200.691 us; speedup vs baseline: 1.2965x; 1.0897x over previous
//
#include <hip/hip_runtime.h>
#include <hip/hip_fp16.h>
#include <math.h>

// Problem constants
#define BB   8
#define HW   4096
#define BHW  32768
#define DIM  256
#define CR   64
#define GC   32
#define NHD  4
#define HC   16
#define NTAP 9
#define NCLS 80

// workspace layout (float offsets)
#define OFF_QP   0u          // q planar   [B][64][H][W] fp32       2,097,152
#define OFF_QT   2097152u    // q pix-major[B*HW][64] fp16          1,048,576 (floats of space)
#define OFF_KT   4194304u    // KV fp16 [BG][HW][2 sub][k16|v16]    2,097,152 (floats of space)
// --- OFF_T span hosts: WBF/AB (k0->k1), T16 (k2->k3) ---
#define OFF_WBF  8388608u    // W_qkv·g1 bf16 [192][256]            24,576 float-slots
#define OFF_AB   8437760u    // A[192], B[192]                      384
#define OFF_T16  8650752u    // t fp16 pix-major [BG][HW][32]       1,048,576 float-slots
// ------------------------------------------------------------------------
#define OFF_OFFB 10485760u   // off planar [BG][18][H][W]           1,179,648
#define OFF_WPT  13762560u   // wproj bf16 [256][64]                8,192 float-slots used
#define OFF_WCT  13778944u   // wcls  bf16 [80][256]                10,240 float-slots used
#define OFF_WFT  13799424u   // woff MFMA A-frags fp16 [2][9][64][8] 4,608 float-slots used

typedef short    bf16x8 __attribute__((ext_vector_type(8)));
typedef _Float16 f16x8  __attribute__((ext_vector_type(8)));
typedef float    f32x4  __attribute__((ext_vector_type(4)));

__device__ __forceinline__ unsigned short f2bf(float f) {
    unsigned u = __float_as_uint(f);
    unsigned r = u + 0x7FFFu + ((u >> 16) & 1u);   // round-to-nearest-even
    return (unsigned short)(r >> 16);
}

// ---------------- k0: weight prep (fully parallel) ----------------
__global__ __launch_bounds__(256) void k0_prep(
    const float* __restrict__ wqkv, const float* __restrict__ g1,
    const float* __restrict__ b1, const float* __restrict__ woff,
    const float* __restrict__ wproj, const float* __restrict__ wcls,
    float* __restrict__ ws)
{
    const int t = threadIdx.x;
    const int blk = blockIdx.x;
    if (blk < 192) {
        const int o = blk;
        unsigned short* wbf = (unsigned short*)(ws + OFF_WBF);
        wbf[o * 256 + t] = f2bf(wqkv[o * 256 + t] * g1[t]);
    } else if (blk < 448) {
        const int r = blk - 192;   // 0..255
        unsigned short* wpb = (unsigned short*)(ws + OFF_WPT);
        unsigned short* wcb = (unsigned short*)(ws + OFF_WCT);
        if (t < 64) wpb[r * 64 + t] = f2bf(wproj[r * 64 + t]);
        if (r < 80) wcb[r * 256 + t] = f2bf(wcls[r * 256 + t]);
    } else if (blk < 640) {
        const int o = blk - 448;   // 0..191
        __shared__ float sa[4], sb[4];
        float w = wqkv[o * 256 + t];
        float a = w * g1[t];
        float bb = w * b1[t];
        #pragma unroll
        for (int off = 1; off < 64; off <<= 1) {
            a  += __shfl_xor(a,  off, 64);
            bb += __shfl_xor(bb, off, 64);
        }
        const int wv = t >> 6;
        if ((t & 63) == 0) { sa[wv] = a; sb[wv] = bb; }
        __syncthreads();
        if (t == 0) {
            ws[OFF_AB + o]       = sa[0] + sa[1] + sa[2] + sa[3];
            ws[OFF_AB + 192 + o] = sb[0] + sb[1] + sb[2] + sb[3];
        }
    } else {
        // wfA[m][wo][lane][j]: value = W[o = m*16 + (lane&15)][ic = (lane>>4)*8 + j] at tap wo
        int idx = (blk - 640) * 256 + t;   // 0..9215
        if (idx < 2 * 9 * 64 * 8) {
            int j = idx & 7;
            int lane = (idx >> 3) & 63;
            int mw = idx >> 9;             // 0..17
            int m = mw / 9, wo = mw % 9;
            int o = m * 16 + (lane & 15);
            int ic = (lane >> 4) * 8 + j;
            float v = (o < 18) ? woff[(o * 32 + ic) * 9 + wo] : 0.f;
            ((__half*)(ws + OFF_WFT))[idx] = __float2half(v);
        }
    }
}

// ------ k1: QKV GEMM via bf16 MFMA, LN folded in epilogue, fp16 q/KV out ------
// grid 512 (b = blk&7 XCD-affine, row = blk>>3), block 512 = 8 waves.
__global__ __launch_bounds__(512) void k1_mfma(
    const float* __restrict__ x, float* __restrict__ ws)
{
    __shared__ float tile[64 * 193];   // 49.4 KB transpose tile [px][o] pad 193
    const int t = threadIdx.x;
    const int b = blockIdx.x & 7, row = blockIdx.x >> 3;
    const int wv = __builtin_amdgcn_readfirstlane(t >> 6);
    const int pt = wv & 3, oh = wv >> 2;
    const int lane = t & 63;
    const int quad = lane >> 4, pxl = lane & 15;
    const int colbase = row * 64 + pt * 16 + pxl;
    const unsigned short* wbf = (const unsigned short*)(ws + OFF_WBF);
    const float* AB = ws + OFF_AB;

    f32x4 acc[6];
    #pragma unroll
    for (int ot = 0; ot < 6; ++ot) acc[ot] = (f32x4){0.f, 0.f, 0.f, 0.f};
    float s = 0.f, ss = 0.f;
    const size_t xb0 = (size_t)b * DIM * HW + colbase;

    for (int ks = 0; ks < 8; ++ks) {
        const int cbase = ks * 32 + quad * 8;
        float xv[8];
        #pragma unroll
        for (int j = 0; j < 8; ++j) {
            xv[j] = x[xb0 + (size_t)(cbase + j) * HW];
            s += xv[j]; ss += xv[j] * xv[j];
        }
        union { bf16x8 v; unsigned short u[8]; } bfrag;
        #pragma unroll
        for (int j = 0; j < 8; ++j) bfrag.u[j] = f2bf(xv[j]);
        #pragma unroll
        for (int ot = 0; ot < 6; ++ot) {
            const int orow = (oh * 6 + ot) * 16 + pxl;
            union { float4 f; bf16x8 v; } afrag;
            afrag.f = *(const float4*)&wbf[orow * 256 + cbase];
            acc[ot] = __builtin_amdgcn_mfma_f32_16x16x32_bf16(afrag.v, bfrag.v, acc[ot], 0, 0, 0);
        }
    }

    s  += __shfl_xor(s, 16, 64);  s  += __shfl_xor(s, 32, 64);
    ss += __shfl_xor(ss, 16, 64); ss += __shfl_xor(ss, 32, 64);
    const float m = s * (1.f / 256.f);
    const float rsv = rsqrtf(ss * (1.f / 256.f) - m * m + 1e-5f);

    const int px = pt * 16 + pxl;
    #pragma unroll
    for (int ot = 0; ot < 6; ++ot) {
        #pragma unroll
        for (int r = 0; r < 4; ++r) {
            int o = (oh * 6 + ot) * 16 + quad * 4 + r;
            tile[px * 193 + o] = rsv * (acc[ot][r] - m * AB[o]) + AB[192 + o];
        }
    }
    __syncthreads();

    float*  qp  = ws + OFF_QP;
    __half* qth = (__half*)(ws + OFF_QT);
    __half* kvh = (__half*)(ws + OFF_KT);
    const int colrow = row * 64;
    #pragma unroll
    for (int it = 0; it < 8; ++it) {
        int idx = it * 512 + t;
        int o = idx >> 6, px2 = idx & 63;
        qp[(size_t)(b * 64 + o) * HW + colrow + px2] = tile[px2 * 193 + o];
    }
    #pragma unroll
    for (int it = 0; it < 8; ++it) {
        int idx = it * 512 + t;
        int px2 = idx >> 6, o = idx & 63;
        qth[(size_t)(b * HW + colrow + px2) * 64 + o] = __float2half(tile[px2 * 193 + o]);
    }
    #pragma unroll
    for (int it = 0; it < 4; ++it) {
        int idx = it * 512 + t;
        int px2 = idx >> 5, ch32 = idx & 31;
        int sB = ch32 >> 4, ch = ch32 & 15;
        kvh[(size_t)((2 * b) * HW + colrow + px2) * 64 + sB * 32 + ch]
            = __float2half(tile[px2 * 193 + 64 + ch32]);
    }
    #pragma unroll
    for (int it = 0; it < 4; ++it) {
        int idx = it * 512 + t;
        int px2 = idx >> 5, ch32 = idx & 31;
        int sB = ch32 >> 4, ch = ch32 & 15;
        kvh[(size_t)((2 * b + 1) * HW + colrow + px2) * 64 + sB * 32 + ch]
            = __float2half(tile[px2 * 193 + 96 + ch32]);
    }
    #pragma unroll
    for (int it = 0; it < 4; ++it) {
        int idx = it * 512 + t;
        int px2 = idx >> 5, ch32 = idx & 31;
        int sB = ch32 >> 4, ch = ch32 & 15;
        kvh[(size_t)((2 * b) * HW + colrow + px2) * 64 + sB * 32 + 16 + ch]
            = __float2half(tile[px2 * 193 + 128 + ch32]);
    }
    #pragma unroll
    for (int it = 0; it < 4; ++it) {
        int idx = it * 512 + t;
        int px2 = idx >> 5, ch32 = idx & 31;
        int sB = ch32 >> 4, ch = ch32 & 15;
        kvh[(size_t)((2 * b + 1) * HW + colrow + px2) * 64 + sB * 32 + 16 + ch]
            = __float2half(tile[px2 * 193 + 160 + ch32]);
    }
}

// ------- k2: depthwise 3x3 + LN(32) + GELU; writes t fp16 pix-major [bg][pix][32] -------
__global__ __launch_bounds__(256) void k2_off_feat(
    const float* __restrict__ wdw, const float* __restrict__ g2, const float* __restrict__ b2,
    float* __restrict__ ws)
{
    __shared__ float qtile[3][32][64];              // 24 KB
    __shared__ float rsum[4][64], rsq[4][64], smv[64], srv[64];
    const int t = threadIdx.x;
    const int b = blockIdx.x & 7;
    const int rest = blockIdx.x >> 3;
    const int g = rest & 1;
    const int row = rest >> 1;
    const int bg = b * 2 + g;
    const int p = t & 63;
    const int cq = __builtin_amdgcn_readfirstlane(t >> 6);
    const float* qp = ws + OFF_QP;

    #pragma unroll
    for (int it = 0; it < 6; ++it) {
        int idx = it * 256 + t;
        int rc = idx >> 4;
        int seg = (idx & 15) << 2;
        int dyy = rc >> 5, ch = rc & 31;
        int y = row + dyy - 1;
        float4 v = make_float4(0.f, 0.f, 0.f, 0.f);
        if ((unsigned)y < 64u)
            v = *(const float4*)&qp[(size_t)(b * 64 + g * 32 + ch) * HW + y * 64 + seg];
        *(float4*)&qtile[dyy][ch][seg] = v;
    }
    __syncthreads();

    float vals[8];
    float s = 0.f, ss = 0.f;
    #pragma unroll
    for (int i = 0; i < 8; ++i) {
        int ch = cq * 8 + i;
        float a = 0.f;
        #pragma unroll
        for (int dy = 0; dy < 3; ++dy) {
            #pragma unroll
            for (int dx = 0; dx < 3; ++dx) {
                int xx = p + dx - 1;
                bool vld = (unsigned)xx < 64u;
                float q = qtile[dy][ch][vld ? xx : 0];
                a += (vld ? q : 0.f) * wdw[ch * 9 + dy * 3 + dx];
            }
        }
        vals[i] = a; s += a; ss += a * a;
    }
    rsum[cq][p] = s; rsq[cq][p] = ss;
    __syncthreads();
    if (t < 64) {
        float S = rsum[0][t] + rsum[1][t] + rsum[2][t] + rsum[3][t];
        float Q = rsq[0][t] + rsq[1][t] + rsq[2][t] + rsq[3][t];
        float m = S * (1.f / 32.f);
        float v = Q * (1.f / 32.f) - m * m;
        smv[t] = m; srv[t] = rsqrtf(v + 1e-5f);
    }
    __syncthreads();
    float m = smv[p], rv = srv[p];
    __half* tb16 = (__half*)(ws + OFF_T16);
    #pragma unroll
    for (int i = 0; i < 8; ++i) {
        int ch = cq * 8 + i;
        float u = (vals[i] - m) * rv * g2[ch] + b2[ch];
        vals[i] = 0.5f * u * (1.f + erff(u * 0.70710678118654752f));
    }
    union { float4 f; __half2 h[4]; } o16;
    #pragma unroll
    for (int i = 0; i < 4; ++i) o16.h[i] = __floats2half2_rn(vals[2 * i], vals[2 * i + 1]);
    *(float4*)&tb16[((size_t)bg * HW + row * 64 + p) * 32 + cq * 8] = o16.f;
}

// ------- k3: 3x3 conv 32->18 as implicit-GEMM fp16 MFMA + tanh*5 + base offset -------
__global__ __launch_bounds__(256) void k3_mfma(
    const float* __restrict__ boff, const float* __restrict__ off_in,
    float* __restrict__ ws)
{
    const int t = threadIdx.x;
    const int b = blockIdx.x & 7;
    const int rest = blockIdx.x >> 3;     // 6 bits: g | rowgrp(4) | xh
    const int g = rest & 1;
    const int rowgrp = (rest >> 1) & 15;
    const int xh = rest >> 5;
    const int wv = __builtin_amdgcn_readfirstlane(t >> 6);
    const int lane = t & 63;
    const int quad = lane >> 4, pxl = lane & 15;
    const int row = rowgrp * 4 + wv;
    const int bg = b * 2 + g;
    const __half* t16 = (const __half*)(ws + OFF_T16);
    const __half* wfA = (const __half*)(ws + OFF_WFT);

    f32x4 acc[2][2];   // [px-tile][m-tile]
    #pragma unroll
    for (int i = 0; i < 2; ++i)
        #pragma unroll
        for (int j = 0; j < 2; ++j) acc[i][j] = (f32x4){0.f, 0.f, 0.f, 0.f};

    union FH { float4 f; f16x8 h; };
    #pragma unroll
    for (int wo = 0; wo < 9; ++wo) {
        const int dy = wo / 3, dx = wo % 3;
        const int y = row + dy - 1;
        const bool yv = (unsigned)y < 64u;
        FH a0, a1;
        a0.f = *(const float4*)&wfA[(size_t)((0 * 9 + wo) * 64 + lane) * 8];
        a1.f = *(const float4*)&wfA[(size_t)((1 * 9 + wo) * 64 + lane) * 8];
        #pragma unroll
        for (int tile = 0; tile < 2; ++tile) {
            const int x = xh * 32 + tile * 16 + pxl + dx - 1;
            FH bf;
            bf.f = make_float4(0.f, 0.f, 0.f, 0.f);
            if (yv && (unsigned)x < 64u)
                bf.f = *(const float4*)&t16[((size_t)bg * HW + y * 64 + x) * 32 + quad * 8];
            acc[tile][0] = __builtin_amdgcn_mfma_f32_16x16x32_f16(a0.h, bf.h, acc[tile][0], 0, 0, 0);
            acc[tile][1] = __builtin_amdgcn_mfma_f32_16x16x32_f16(a1.h, bf.h, acc[tile][1], 0, 0, 0);
        }
    }

    float* ob = ws + OFF_OFFB;
    #pragma unroll
    for (int tile = 0; tile < 2; ++tile) {
        const int px = xh * 32 + tile * 16 + pxl;
        #pragma unroll
        for (int mi = 0; mi < 2; ++mi) {
            #pragma unroll
            for (int r = 0; r < 4; ++r) {
                int o = mi * 16 + quad * 4 + r;
                if (o < 18) {
                    float v = acc[tile][mi][r] + boff[o];
                    v = tanhf(v) * 5.0f + off_in[(size_t)(b * 18 + o) * HW + row * 64 + px];
                    ob[(size_t)(bg * 18 + o) * HW + row * 64 + px] = v;
                }
            }
        }
    }
}

// ---- k45: deformable gather + softmax attn FUSED with proj+residual+cls ----
// grid 2048 (b = blk&7 XCD-affine, chunk = blk>>3), block 256 = 4 waves, 16 px/block.
// Phase A (attn): identical math to old k4; output lands in LDS ao_l[16px][64ch] bf16.
// Phase B (proj): 4 waves split 16 o-tiles (4 each) -> tmp[16][264] bf16 LDS.
// Phase C (cls):  wave wv handles oc-tiles {wv, wv+4<5}; writes out.
__global__ __launch_bounds__(256, 4) void k45_attn_proj(
    const float* __restrict__ rpb, const float* __restrict__ x,
    const float* __restrict__ bproj, const float* __restrict__ bcls,
    float* __restrict__ ws, float* __restrict__ out)
{
    __shared__ float rpb_l[NHD * NTAP * HC];      // 2.3 KB
    __shared__ unsigned short ao_l[16][72];       // 2.3 KB bf16, pad 8
    __shared__ unsigned short tmp[16][264];       // 8.25 KB bf16, pad 8
    for (int i = threadIdx.x; i < NHD * NTAP * HC; i += 256) rpb_l[i] = rpb[i];
    __syncthreads();

    const int t = threadIdx.x;
    const int wave = __builtin_amdgcn_readfirstlane(t >> 6);
    const int g = wave & 1, pxh = wave >> 1;
    const int lane = t & 63;
    const int pxl = lane & 7;
    const int prt = lane >> 3;
    const int s    = prt >> 2;
    const int half = (prt >> 1) & 1;
    const int j    = prt & 1;
    const int b = blockIdx.x & 7;
    const int chunk = blockIdx.x >> 3;          // 0..255
    const int hw_base = chunk * 16;
    const int hw = hw_base + pxh * 8 + pxl;
    const int pix = b * HW + hw;
    const int bg = b * 2 + g;
    const int head = g * 2 + s;

    const __half* qth = (const __half*)(ws + OFF_QT);
    const __half* kvh = (const __half*)(ws + OFF_KT);
    const float*  ob  = ws + OFF_OFFB;

    // hoist all 18 offset loads (independent; issue back-to-back)
    float rr_[NTAP], cc_[NTAP];
    #pragma unroll
    for (int n = 0; n < NTAP; ++n) {
        rr_[n] = ob[(size_t)(bg * 18 + 2 * n) * HW + hw];
        cc_[n] = ob[(size_t)(bg * 18 + 2 * n + 1) * HW + hw];
    }

    union F4H { float4 f; __half2 h[4]; };
    F4H qld;
    qld.f = *(const float4*)&qth[(size_t)pix * 64 + g * 32 + s * 16 + j * 8];
    const float qs = half ? 0.0f : 0.25f;
    float qv[8];
    #pragma unroll
    for (int i = 0; i < 4; ++i) {
        float2 q2 = __half22float2(qld.h[i]);
        qv[2 * i] = q2.x * qs; qv[2 * i + 1] = q2.y * qs;
    }

    const float4* rb4 = (const float4*)(rpb_l + head * (NTAP * HC) + j * 8);
    const __half* kvp = kvh + (size_t)(bg * HW) * 64 + prt * 8;

    __half2 av[NTAP][4];
    float logit[NTAP];

    #pragma unroll
    for (int n = 0; n < NTAP; ++n) {
        float r = rr_[n];
        float c = cc_[n];
        float y0f = floorf(r), x0f = floorf(c);
        float fy = r - y0f, fx = c - x0f;
        int iy0 = (int)y0f, ix0 = (int)x0f;
        float wts[4] = { (1.f - fx) * (1.f - fy), fx * (1.f - fy),
                         (1.f - fx) * fy,         fx * fy };
        __half2 acc0 = __float2half2_rn(0.f), acc1 = acc0, acc2 = acc0, acc3 = acc0;
        #pragma unroll
        for (int corner = 0; corner < 4; ++corner) {
            int cxx = ix0 + (corner & 1);
            int cyy = iy0 + (corner >> 1);
            bool vld = ((unsigned)cxx < 64u) && ((unsigned)cyy < 64u);
            float w = vld ? wts[corner] : 0.f;
            int cxc = min(max(cxx, 0), 63);
            int cyc = min(max(cyy, 0), 63);
            F4H kv;
            kv.f = *(const float4*)&kvp[(size_t)(cyc * 64 + cxc) * 64];
            __half2 w2 = __float2half2_rn(w);
            acc0 = __hfma2(kv.h[0], w2, acc0);
            acc1 = __hfma2(kv.h[1], w2, acc1);
            acc2 = __hfma2(kv.h[2], w2, acc2);
            acc3 = __hfma2(kv.h[3], w2, acc3);
        }
        av[n][0] = acc0; av[n][1] = acc1; av[n][2] = acc2; av[n][3] = acc3;
        float4 r0 = rb4[n * 4], r1 = rb4[n * 4 + 1];
        float2 a0 = __half22float2(acc0), a1 = __half22float2(acc1);
        float2 a2 = __half22float2(acc2), a3 = __half22float2(acc3);
        float part = qv[0] * (a0.x + r0.x) + qv[1] * (a0.y + r0.y)
                   + qv[2] * (a1.x + r0.z) + qv[3] * (a1.y + r0.w)
                   + qv[4] * (a2.x + r1.x) + qv[5] * (a2.y + r1.y)
                   + qv[6] * (a3.x + r1.z) + qv[7] * (a3.y + r1.w);
        part += __shfl_xor(part, 8, 64);
        part += __shfl_xor(part, 16, 64);
        logit[n] = part;
    }

    float m = logit[0];
    #pragma unroll
    for (int n = 1; n < NTAP; ++n) m = fmaxf(m, logit[n]);
    float l = 0.f;
    #pragma unroll
    for (int n = 0; n < NTAP; ++n) { logit[n] = __expf(logit[n] - m); l += logit[n]; }
    const float inv = 1.f / l;

    __half2 o0 = __float2half2_rn(0.f), o1 = o0, o2 = o0, o3 = o0;
    #pragma unroll
    for (int n = 0; n < NTAP; ++n) {
        __half2 p2 = __float2half2_rn(logit[n]);
        o0 = __hfma2(av[n][0], p2, o0);
        o1 = __hfma2(av[n][1], p2, o1);
        o2 = __hfma2(av[n][2], p2, o2);
        o3 = __hfma2(av[n][3], p2, o3);
    }
    if (half) {   // v-lanes deposit ao bf16 into LDS [16 px][64 ch]
        const int cb = head * 16 + j * 8;
        float2 f0 = __half22float2(o0), f1 = __half22float2(o1);
        float2 f2 = __half22float2(o2), f3 = __half22float2(o3);
        union { float4 f; unsigned short u[8]; } pk;
        pk.u[0] = f2bf(f0.x * inv); pk.u[1] = f2bf(f0.y * inv);
        pk.u[2] = f2bf(f1.x * inv); pk.u[3] = f2bf(f1.y * inv);
        pk.u[4] = f2bf(f2.x * inv); pk.u[5] = f2bf(f2.y * inv);
        pk.u[6] = f2bf(f3.x * inv); pk.u[7] = f2bf(f3.y * inv);
        *(float4*)&ao_l[pxh * 8 + pxl][cb] = pk.f;
    }
    __syncthreads();

    // ---------------- Phase B: proj (64->256) + bias + residual ----------------
    const int q4  = lane >> 4;        // quad
    const int p16 = lane & 15;        // pixel within block tile
    const unsigned short* wpb = (const unsigned short*)(ws + OFF_WPT);
    const unsigned short* wcb = (const unsigned short*)(ws + OFF_WCT);

    union FB { float4 f; bf16x8 v; };
    FB bf0, bf1;
    bf0.f = *(const float4*)&ao_l[p16][q4 * 8];
    bf1.f = *(const float4*)&ao_l[p16][32 + q4 * 8];

    #pragma unroll
    for (int ot = wave * 4; ot < wave * 4 + 4; ++ot) {
        f32x4 acc = (f32x4){0.f, 0.f, 0.f, 0.f};
        FB a0, a1;
        const int om = ot * 16 + p16;
        a0.f = *(const float4*)&wpb[om * 64 + q4 * 8];
        a1.f = *(const float4*)&wpb[om * 64 + 32 + q4 * 8];
        acc = __builtin_amdgcn_mfma_f32_16x16x32_bf16(a0.v, bf0.v, acc, 0, 0, 0);
        acc = __builtin_amdgcn_mfma_f32_16x16x32_bf16(a1.v, bf1.v, acc, 0, 0, 0);
        union { unsigned short u[4]; } pk;
        #pragma unroll
        for (int r = 0; r < 4; ++r) {
            int o = ot * 16 + q4 * 4 + r;
            float v = acc[r] + bproj[o] + x[(size_t)(b * DIM + o) * HW + hw_base + p16];
            pk.u[r] = f2bf(v);
        }
        *(ushort4*)&tmp[p16][ot * 16 + q4 * 4] = *(ushort4*)pk.u;
    }
    __syncthreads();

    // ---------------- Phase C: cls (256->80) ----------------
    #pragma unroll
    for (int oc = wave; oc < 5; oc += 4) {
        f32x4 acc2 = (f32x4){0.f, 0.f, 0.f, 0.f};
        #pragma unroll
        for (int kc = 0; kc < 8; ++kc) {
            FB bb, aa;
            bb.f = *(const float4*)&tmp[p16][kc * 32 + q4 * 8];
            aa.f = *(const float4*)&wcb[(oc * 16 + p16) * 256 + kc * 32 + q4 * 8];
            acc2 = __builtin_amdgcn_mfma_f32_16x16x32_bf16(aa.v, bb.v, acc2, 0, 0, 0);
        }
        #pragma unroll
        for (int r = 0; r < 4; ++r) {
            int o = oc * 16 + q4 * 4 + r;
            out[(size_t)(b * NCLS + o) * HW + hw_base + p16] = acc2[r] + bcls[o];
        }
    }
}

extern "C" void kernel_launch(void* const* d_in, const int* in_sizes, int n_in,
                              void* d_out, int out_size, void* d_ws, size_t ws_size,
                              hipStream_t stream)
{
    const float* x     = (const float*)d_in[0];
    const float* off   = (const float*)d_in[1];
    const float* g1    = (const float*)d_in[2];
    const float* b1    = (const float*)d_in[3];
    const float* wqkv  = (const float*)d_in[4];
    const float* wdw   = (const float*)d_in[5];
    const float* g2    = (const float*)d_in[6];
    const float* b2    = (const float*)d_in[7];
    const float* woff  = (const float*)d_in[8];
    const float* boff  = (const float*)d_in[9];
    const float* rpb   = (const float*)d_in[10];
    const float* wproj = (const float*)d_in[11];
    const float* bproj = (const float*)d_in[12];
    const float* wcls  = (const float*)d_in[13];
    const float* bcls  = (const float*)d_in[14];
    float* ws  = (float*)d_ws;
    float* out = (float*)d_out;

    hipLaunchKernelGGL(k0_prep,       dim3(676),  dim3(256), 0, stream, wqkv, g1, b1, woff, wproj, wcls, ws);
    hipLaunchKernelGGL(k1_mfma,       dim3(512),  dim3(512), 0, stream, x, ws);
    hipLaunchKernelGGL(k2_off_feat,   dim3(1024), dim3(256), 0, stream, wdw, g2, b2, ws);
    hipLaunchKernelGGL(k3_mfma,       dim3(512),  dim3(256), 0, stream, boff, off, ws);
    hipLaunchKernelGGL(k45_attn_proj, dim3(2048), dim3(256), 0, stream, rpb, x, bproj, bcls, ws, out);
}